// Round 15
// baseline (200.353 us; speedup 1.0000x reference)
//
#include <hip/hip_runtime.h>
#include <hip/hip_bf16.h>
#include <cstddef>

#define BATCH 4
#define CH 256
#define HH 96
#define WW 96
#define HWN (HH*WW)               // 9216
#define NTOT (BATCH*CH*HWN)       // 9437184
#define XT_H 98
#define XT_W 98
#define XT_PLANE (XT_H*XT_W*CH)   // per-batch elements in xt (bf16)

typedef __attribute__((ext_vector_type(16))) float f32x16;
typedef __attribute__((ext_vector_type(8))) __bf16 bfrag;
typedef __attribute__((ext_vector_type(8))) unsigned short u16x8;

static __device__ __forceinline__ unsigned short f2bf(float f) {
  unsigned int u = __float_as_uint(f);
  unsigned int r = (u + 0x7fffu + ((u >> 16) & 1u)) >> 16;
  return (unsigned short)r;
}
static __device__ __forceinline__ float bf2f(unsigned short s) {
  return __uint_as_float(((unsigned int)s) << 16);
}

// async global->LDS, 16B per lane; LDS dest = wave-uniform base + lane*16
static __device__ __forceinline__ void gload16(const unsigned short* g,
                                               unsigned short* l) {
  __builtin_amdgcn_global_load_lds(
      (const __attribute__((address_space(1))) unsigned int*)g,
      (__attribute__((address_space(3))) unsigned int*)l, 16, 0, 0);
}

// ---------------------------------------------------------------------------
// Kernel 1a: stage-1 GEMVs, wide-parallel (unchanged R9).
// ---------------------------------------------------------------------------
__global__ __launch_bounds__(256) void params_stage1_kernel(
    const float* __restrict__ para, const float* __restrict__ style,
    const float* __restrict__ cw,  const float* __restrict__ cb,
    const float* __restrict__ a1w, const float* __restrict__ a1b,
    const float* __restrict__ a2w, const float* __restrict__ a2b,
    float* __restrict__ pcbuf, float* __restrict__ a1buf, float* __restrict__ a2buf)
{
  __shared__ float s_in[256];
  __shared__ float red[256];
  int part = blockIdx.x, b = blockIdx.y, t = threadIdx.x;
  s_in[t] = (part < 4) ? para[b*256 + t] : style[b*256 + t];
  __syncthreads();
  if (part < 4) {
    int o = t & 63, ks = t >> 6, co0 = part * 64;
    const float* wcol = cw + co0 + o;
    float acc = 0.f;
    #pragma unroll 8
    for (int i = 0; i < 64; i++) {
      int k = ks * 64 + i;
      acc = fmaf(s_in[k], wcol[k * 256], acc);
    }
    red[t] = acc;
    __syncthreads();
    if (t < 64) {
      float s = red[t] + red[t + 64] + red[t + 128] + red[t + 192];
      pcbuf[b*256 + co0 + t] = fmaxf(s + cb[co0 + t], 0.f);
    }
  } else {
    const float* w  = (part == 4) ? a1w : a2w;
    const float* bb = (part == 4) ? a1b : a2b;
    float* outp = (part == 4) ? a1buf : a2buf;
    int o = t & 127, ks = t >> 7;
    const float* wcol = w + o;
    float acc = 0.f;
    #pragma unroll 8
    for (int i = 0; i < 128; i++) {
      int k = ks * 128 + i;
      acc = fmaf(s_in[k], wcol[k * 128], acc);
    }
    red[t] = acc;
    __syncthreads();
    if (t < 128) {
      float s = red[t] + red[t + 128];
      outp[b*128 + t] = fmaxf(s + bb[t], 0.f);
    }
  }
}

// ---------------------------------------------------------------------------
// Kernel 1b: stage-2 params (unchanged R9).
// ---------------------------------------------------------------------------
__global__ __launch_bounds__(256) void params_stage2_kernel(
    const float* __restrict__ pcbuf, const float* __restrict__ a1buf,
    const float* __restrict__ a2buf,
    const float* __restrict__ sw,  const float* __restrict__ sb,
    const float* __restrict__ rw,  const float* __restrict__ rb,
    const float* __restrict__ tw,  const float* __restrict__ tb,
    const float* __restrict__ g1w, const float* __restrict__ g1b,
    const float* __restrict__ b1w, const float* __restrict__ b1b,
    const float* __restrict__ g2w, const float* __restrict__ g2b,
    const float* __restrict__ b2w, const float* __restrict__ b2b,
    float* __restrict__ warp, float* __restrict__ gb1, float* __restrict__ gb2)
{
  __shared__ float s_pc[256], s_a1[128], s_a2[128];
  __shared__ float red[8][4][16];
  int co0 = blockIdx.x * 16, b = blockIdx.y, t = threadIdx.x;
  s_pc[t] = pcbuf[b*256 + t];
  if (t < 128) s_a1[t] = a1buf[b*128 + t];
  else         s_a2[t - 128] = a2buf[b*128 + (t - 128)];
  __syncthreads();

  int cl = t & 15, klane = t >> 4;
  int c = co0 + cl;
  const float2* tw2 = (const float2*)tw;
  float ds = 0.f, dr = 0.f, dtx = 0.f, dty = 0.f;
  float g1 = 0.f, be1 = 0.f, g2 = 0.f, be2 = 0.f;
  #pragma unroll 4
  for (int kk = 0; kk < 16; kk++) {
    int i = klane * 16 + kk;
    float p = s_pc[i];
    ds  = fmaf(p, sw[i*256 + c], ds);
    dr  = fmaf(p, rw[i*256 + c], dr);
    float2 tv = tw2[i*256 + c];
    dtx = fmaf(p, tv.x, dtx);
    dty = fmaf(p, tv.y, dty);
  }
  #pragma unroll 4
  for (int kk = 0; kk < 8; kk++) {
    int i = klane * 8 + kk;
    float a = s_a1[i];
    g1  = fmaf(a, g1w[i*256 + c], g1);
    be1 = fmaf(a, b1w[i*256 + c], be1);
    float a2v = s_a2[i];
    g2  = fmaf(a2v, g2w[i*256 + c], g2);
    be2 = fmaf(a2v, b2w[i*256 + c], be2);
  }
  ds  += __shfl_down(ds, 32, 64);  ds  += __shfl_down(ds, 16, 64);
  dr  += __shfl_down(dr, 32, 64);  dr  += __shfl_down(dr, 16, 64);
  dtx += __shfl_down(dtx, 32, 64); dtx += __shfl_down(dtx, 16, 64);
  dty += __shfl_down(dty, 32, 64); dty += __shfl_down(dty, 16, 64);
  g1  += __shfl_down(g1, 32, 64);  g1  += __shfl_down(g1, 16, 64);
  be1 += __shfl_down(be1, 32, 64); be1 += __shfl_down(be1, 16, 64);
  g2  += __shfl_down(g2, 32, 64);  g2  += __shfl_down(g2, 16, 64);
  be2 += __shfl_down(be2, 32, 64); be2 += __shfl_down(be2, 16, 64);
  int wv = t >> 6;
  if ((t & 63) < 16) {
    red[0][wv][cl] = ds;  red[1][wv][cl] = dr;
    red[2][wv][cl] = dtx; red[3][wv][cl] = dty;
    red[4][wv][cl] = g1;  red[5][wv][cl] = be1;
    red[6][wv][cl] = g2;  red[7][wv][cl] = be2;
  }
  __syncthreads();
  if (t < 16) {
    float v[8];
    #pragma unroll
    for (int o = 0; o < 8; o++)
      v[o] = red[o][0][t] + red[o][1][t] + red[o][2][t] + red[o][3][t];
    int cc = co0 + t;
    int bc = b*256 + cc;
    float scale = 2.f / (1.f + expf(-(v[0] + sb[cc])));
    float ang = tanhf(v[1] + rb[cc]) * 3.14159f;
    float sn, cs;
    sincosf(ang, &sn, &cs);
    warp[bc*4 + 0] = cs * scale;
    warp[bc*4 + 1] = sn * scale;
    warp[bc*4 + 2] = tanhf(v[2] + tb[2*cc]);
    warp[bc*4 + 3] = tanhf(v[3] + tb[2*cc + 1]);
    gb1[bc*2]     = v[4] + g1b[cc];
    gb1[bc*2 + 1] = v[5] + b1b[cc];
    gb2[bc*2]     = v[6] + g2b[cc];
    gb2[bc*2 + 1] = v[7] + b2b[cc];
  }
}

// ---------------------------------------------------------------------------
// Kernel 2: weight preconversion (unchanged).
// wf[coblk4][ks16][tap9][m2][lane64][8]
// ---------------------------------------------------------------------------
__global__ __launch_bounds__(256) void prep_weights_kernel(
    const float* __restrict__ w1, const float* __restrict__ w2,
    unsigned short* __restrict__ wf1, unsigned short* __restrict__ wf2)
{
  int co = blockIdx.x & 255;
  const float* src = (blockIdx.x < 256) ? w1 : w2;
  unsigned short* dst = (blockIdx.x < 256) ? wf1 : wf2;
  int ci = threadIdx.x;
  int coblk = co >> 6, m = (co >> 5) & 1;
  int l = (co & 31) | (((ci >> 3) & 1) << 5);
  int ks = ci >> 4, j = ci & 7;
  const float* p = src + ((size_t)co * 256 + ci) * 9;
  #pragma unroll
  for (int tap = 0; tap < 9; tap++) {
    size_t idx = (((size_t)((coblk * 16 + ks) * 9 + tap) * 2 + m) * 64 + l) * 8 + j;
    dst[idx] = f2bf(p[tap]);
  }
}

// ---------------------------------------------------------------------------
// Kernel 3: AdaAT warp + fused stats + AdaIN-1 + lrelu + bf16 cvt (R14).
// ---------------------------------------------------------------------------
__global__ __launch_bounds__(256) void adaat_kernel(
    const float* __restrict__ fm, const float* __restrict__ warp,
    const float* __restrict__ gb1, unsigned short* __restrict__ tout)
{
  __shared__ float s[96 * 100];
  int bc = blockIdx.x;
  int b = bc >> 8, c = bc & 255;
  float csc = warp[bc*4 + 0], ssc = warp[bc*4 + 1];
  float tx = warp[bc*4 + 2], ty = warp[bc*4 + 3];

  const float axw = csc * (96.f / 95.f);
  const float axh = -ssc * (96.f / 95.f);
  const float ax0 = 48.f * (tx - csc + ssc) + 47.5f;
  const float ayw = ssc * (96.f / 95.f);
  const float ayh = csc * (96.f / 95.f);
  const float ay0 = 48.f * (ty - ssc - csc) + 47.5f;

  float iz = 256.f * (float)c / 255.f - 0.5f;
  float z0f = floorf(iz);
  float wz = iz - z0f;
  int z0 = (int)z0f;
  const float* p0 = (z0 >= 0) ? fm + (size_t)(b*256 + z0) * HWN : nullptr;
  const float* p1 = (z0 + 1 < 256) ? fm + (size_t)(b*256 + z0 + 1) * HWN : nullptr;
  float w0 = 1.f - wz, w1 = wz;

  int t = threadIdx.x;
  const float4* q0 = (const float4*)p0;
  const float4* q1 = (const float4*)p1;
  for (int i = t; i < 2304; i += 256) {
    int row = i / 24, col = i - row * 24;
    float4 r = {0.f, 0.f, 0.f, 0.f};
    if (q0) {
      float4 v = q0[i];
      r.x = w0 * v.x; r.y = w0 * v.y; r.z = w0 * v.z; r.w = w0 * v.w;
    }
    if (q1) {
      float4 v = q1[i];
      r.x = fmaf(w1, v.x, r.x); r.y = fmaf(w1, v.y, r.y);
      r.z = fmaf(w1, v.z, r.z); r.w = fmaf(w1, v.w, r.w);
    }
    *(float4*)&s[row * 100 + col * 4] = r;
  }
  __syncthreads();

  int h = t / 96, w = t - (t / 96) * 96;
  float vals[36];
  float sum = 0.f, sumsq = 0.f;
  #pragma unroll
  for (int k = 0; k < 36; k++) {
    float ix = fmaf(axw, (float)w, fmaf(axh, (float)h, ax0));
    float iy = fmaf(ayw, (float)w, fmaf(ayh, (float)h, ay0));
    float x0f = floorf(ix), y0f = floorf(iy);
    float wx = ix - x0f, wy = iy - y0f;
    int x0 = (int)x0f, y0 = (int)y0f;
    int x0c = min(max(x0, 0), 95), x1c = min(max(x0 + 1, 0), 95);
    int y0c = min(max(y0, 0), 95), y1c = min(max(y0 + 1, 0), 95);
    bool vx0 = (unsigned)x0 < 96u, vx1 = (unsigned)(x0 + 1) < 96u;
    bool vy0 = (unsigned)y0 < 96u, vy1 = (unsigned)(y0 + 1) < 96u;
    float a00 = s[y0c * 100 + x0c], a01 = s[y0c * 100 + x1c];
    float a10 = s[y1c * 100 + x0c], a11 = s[y1c * 100 + x1c];
    float wxm = 1.f - wx, wym = 1.f - wy;
    float w00 = (vy0 && vx0) ? wym * wxm : 0.f;
    float w01 = (vy0 && vx1) ? wym * wx  : 0.f;
    float w10 = (vy1 && vx0) ? wy * wxm  : 0.f;
    float w11 = (vy1 && vx1) ? wy * wx   : 0.f;
    float v = w00 * a00;
    v = fmaf(w01, a01, v);
    v = fmaf(w10, a10, v);
    v = fmaf(w11, a11, v);
    vals[k] = v;
    sum += v;
    sumsq = fmaf(v, v, sumsq);
    int wn = w + 64;
    int carry = (wn >= 96) ? 1 : 0;
    w = wn - (carry ? 96 : 0);
    h += 2 + carry;
  }

  for (int off = 32; off > 0; off >>= 1) {
    sum   += __shfl_down(sum, off, 64);
    sumsq += __shfl_down(sumsq, off, 64);
  }
  __shared__ float rs[4], rq[4], sbi[2];
  int lane = t & 63, wvi = t >> 6;
  if (lane == 0) { rs[wvi] = sum; rq[wvi] = sumsq; }
  __syncthreads();
  if (t == 0) {
    float S = rs[0] + rs[1] + rs[2] + rs[3];
    float Q = rq[0] + rq[1] + rq[2] + rq[3];
    float m = S * (1.f / 9216.f);
    float var = Q * (1.f / 9216.f) - m * m;
    float rstd = rsqrtf(var + 1e-5f);
    float sc = (1.f + gb1[bc*2]) * rstd;
    sbi[0] = sc;
    sbi[1] = gb1[bc*2 + 1] - m * sc;
  }
  __syncthreads();
  float sc = sbi[0], bi = sbi[1];
  unsigned short* dst = tout + (size_t)bc * HWN + t;
  #pragma unroll
  for (int k = 0; k < 36; k++) {
    float y = fmaf(vals[k], sc, bi);
    y = (y >= 0.f) ? y : 0.2f * y;
    dst[k * 256] = f2bf(y);
  }
}

// ---------------------------------------------------------------------------
// Kernel 4: finalize per-(b,co) stats from conv1 partials (unchanged).
// ---------------------------------------------------------------------------
__global__ __launch_bounds__(256) void finalize_stats_kernel(
    const float* __restrict__ psum, const float* __restrict__ gb,
    float* __restrict__ nrm)
{
  int bc = blockIdx.x * 256 + threadIdx.x;
  int b = bc >> 8, co = bc & 255;
  float S = 0.f, Q = 0.f;
  for (int j = 0; j < 96; j++) {
    const float* p = psum + ((((size_t)b * 48 + (j >> 1)) * 2 + (j & 1)) * 256 + co) * 2;
    S += p[0];
    Q += p[1];
  }
  float m = S * (1.f / 9216.f);
  float var = Q * (1.f / 9216.f) - m * m;
  float rstd = rsqrtf(var + 1e-5f);
  float sc = (1.f + gb[bc*2]) * rstd;
  nrm[bc*2] = sc;
  nrm[bc*2 + 1] = gb[bc*2 + 1] - m * sc;
}

// ---------------------------------------------------------------------------
// Kernel 5: pure bf16 transpose t(plane-major) -> xt layout + borders (R14).
// ---------------------------------------------------------------------------
__global__ __launch_bounds__(256) void transpose_kernel(
    const unsigned short* __restrict__ tb, unsigned short* __restrict__ xt)
{
  int hi = blockIdx.x;
  int b  = blockIdx.y;
  unsigned short* dst = xt + (size_t)b * XT_PLANE + (size_t)hi * (XT_W * CH);
  int t = threadIdx.x;
  int h = hi - 1;
  u16x8 zero = {0,0,0,0,0,0,0,0};
  if (h < 0 || h >= 96) {
    for (int c = t; c < XT_W * CH / 8; c += 256) ((u16x8*)dst)[c] = zero;
    return;
  }
  __shared__ unsigned short s[96 * 256];  // [w][ci]
  int ci = t;
  const unsigned short* src = tb + ((size_t)(b*256 + ci)) * HWN + h * 96;
  #pragma unroll
  for (int wg = 0; wg < 12; wg++) {
    u16x8 v = *(const u16x8*)(src + wg * 8);
    #pragma unroll
    for (int j = 0; j < 8; j++) s[(wg*8 + j) * 256 + ci] = v[j];
  }
  __syncthreads();
  for (int c = t; c < 98 * 32; c += 256) {
    int w = c >> 5, p = c & 31;
    u16x8 v = zero;
    if (w >= 1 && w <= 96) v = *(const u16x8*)&s[(w - 1) * 256 + p * 8];
    ((u16x8*)dst)[c] = v;
  }
}

// ---------------------------------------------------------------------------
// Kernel 5b: elementwise AdaIN-2 + lrelu on bf16 xt2, in place (unchanged).
// ---------------------------------------------------------------------------
__global__ __launch_bounds__(256) void norm2_kernel(
    unsigned short* __restrict__ xt, const float* __restrict__ nrm)
{
  int hi = blockIdx.x, b = blockIdx.y;
  unsigned short* row = xt + (size_t)b * XT_PLANE + (size_t)hi * (XT_W * CH);
  int t = threadIdx.x;
  u16x8 zero = {0,0,0,0,0,0,0,0};
  if (hi == 0 || hi == 97) {
    for (int c = t; c < XT_W * CH / 8; c += 256) ((u16x8*)row)[c] = zero;
    return;
  }
  int p = t & 31;
  float sc[8], bi[8];
  #pragma unroll
  for (int j = 0; j < 8; j++) {
    int co = p * 8 + j;
    sc[j] = nrm[(b*256 + co)*2];
    bi[j] = nrm[(b*256 + co)*2 + 1];
  }
  for (int wi = t >> 5; wi < 98; wi += 8) {
    int c = wi * 32 + p;
    if (wi == 0 || wi == 97) { ((u16x8*)row)[c] = zero; continue; }
    u16x8 v = ((u16x8*)row)[c];
    u16x8 o;
    #pragma unroll
    for (int j = 0; j < 8; j++) {
      float x = bf2f(v[j]);
      float y = fmaf(x, sc[j], bi[j]);
      y = (y >= 0.f) ? y : 0.2f * y;
      o[j] = f2bf(y);
    }
    ((u16x8*)row)[c] = o;
  }
}

// ---------------------------------------------------------------------------
// Kernel 6 (R15): conv, dim3 grid (R13 locality); per-ky software-pipelined
// B-fragment double-buffer (bb for ky+1 read BEFORE ky's MFMA cluster so
// LDS latency hides under MFMA issue).
// ---------------------------------------------------------------------------
__global__ __launch_bounds__(256, 3) void conv_mfma_kernel(
    const unsigned short* __restrict__ xt,   // input [4][98][98][256] bf16
    const unsigned short* __restrict__ wf,   // frag layout (see prep)
    const float* __restrict__ cb,
    float* __restrict__ out,                 // f32 output (conv2 path)
    unsigned short* __restrict__ xt2,        // bf16 transposed output (conv1)
    float* __restrict__ psum)                // partials or nullptr
{
  __shared__ __align__(16) unsigned short s_in[2][6528];

  int hb = blockIdx.x, coblk = blockIdx.y, b = blockIdx.z;
  int co0 = coblk * 64, h0 = hb * 2;
  int t = threadIdx.x, lane = t & 63, wv = t >> 6;
  int rw = wv >> 1, mh = wv & 1;
  int l31 = lane & 31, lhi = lane >> 5;
  const unsigned short* xtb = xt + (size_t)b * XT_PLANE;

  int pre_g[4];
  #pragma unroll
  for (int i = 0; i < 4; i++) {
    int c = t + i * 256;
    if (c < 784) {
      int r = c / 196;
      int rem = c - r * 196;
      int half = rem / 98;
      int w = rem - half * 98;
      pre_g[i] = ((h0 + r) * 98 + w) * 256 + half * 8;
    }
  }

  f32x16 acc[3];
  #pragma unroll
  for (int nn = 0; nn < 3; nn++)
    #pragma unroll
    for (int i = 0; i < 16; i++) acc[nn][i] = 0.f;

  const unsigned short* wfb = wf + (size_t)(coblk * 16) * 9216 + mh * 512 + lane * 8;

  {
    #pragma unroll
    for (int i = 0; i < 3; i++)
      gload16(xtb + pre_g[i], &s_in[0][(i * 256 + wv * 64) * 8]);
    u16x8 tail0;
    if (t < 16) tail0 = *(const u16x8*)(xtb + pre_g[3]);
    if (t < 16) *(u16x8*)(&s_in[0][(768 + t) * 8]) = tail0;
  }
  bfrag wa[9];
  #pragma unroll
  for (int tap = 0; tap < 9; tap++) wa[tap] = *(const bfrag*)(wfb + tap * 1024);
  __syncthreads();

  int buf = 0;
  u16x8 tail;
  int boff = lhi * 98 * 8 + l31 * 8;   // within a row-pair: [lhi half][l31 px]
  #pragma unroll 1
  for (int ks = 0; ks < 16; ks++) {
    if (ks < 15) {
      int cib = (ks + 1) * 16;
      unsigned short* nb = s_in[buf ^ 1];
      #pragma unroll
      for (int i = 0; i < 3; i++)
        gload16(xtb + pre_g[i] + cib, &nb[(i * 256 + wv * 64) * 8]);
      if (t < 16) tail = *(const u16x8*)(xtb + pre_g[3] + cib);
    }
    const unsigned short* sb = s_in[buf];
    int ksn = (ks < 15) ? (ks + 1) : 15;
    const unsigned short* wkn = wfb + (size_t)ksn * 9216;

    // software pipeline over ky: read bb(ky+1) before MFMA(ky)
    bfrag bbA[9], bbB[9];
    {
      const unsigned short* srow0 = sb + ((rw * 2) * 98) * 8 + boff;
      #pragma unroll
      for (int kx = 0; kx < 3; kx++)
        #pragma unroll
        for (int nn = 0; nn < 3; nn++)
          bbA[kx * 3 + nn] = *(const bfrag*)(srow0 + (nn * 32 + kx) * 8);
    }
    #pragma unroll
    for (int ky = 0; ky < 3; ky++) {
      bfrag* cur = (ky & 1) ? bbB : bbA;
      bfrag* nxt = (ky & 1) ? bbA : bbB;
      if (ky < 2) {
        const unsigned short* srow = sb + (((rw + ky + 1) * 2) * 98) * 8 + boff;
        #pragma unroll
        for (int kx = 0; kx < 3; kx++)
          #pragma unroll
          for (int nn = 0; nn < 3; nn++)
            nxt[kx * 3 + nn] = *(const bfrag*)(srow + (nn * 32 + kx) * 8);
      }
      __builtin_amdgcn_s_setprio(1);
      #pragma unroll
      for (int kx = 0; kx < 3; kx++) {
        int tap = ky * 3 + kx;
        acc[0] = __builtin_amdgcn_mfma_f32_32x32x16_bf16(wa[tap], cur[kx*3+0], acc[0], 0, 0, 0);
        acc[1] = __builtin_amdgcn_mfma_f32_32x32x16_bf16(wa[tap], cur[kx*3+1], acc[1], 0, 0, 0);
        acc[2] = __builtin_amdgcn_mfma_f32_32x32x16_bf16(wa[tap], cur[kx*3+2], acc[2], 0, 0, 0);
        wa[tap] = *(const bfrag*)(wkn + tap * 1024);
      }
      __builtin_amdgcn_s_setprio(0);
    }
    if (ks < 15 && t < 16) *(u16x8*)(&s_in[buf ^ 1][(768 + t) * 8]) = tail;
    __syncthreads();
    buf ^= 1;
  }

  int h = h0 + rw;
  if (psum) {
    // conv1: bf16 transposed output via LDS bounce + stats partials
    unsigned short* tbl = (unsigned short*)s_in;   // [2 rows][96 px][68 co-pad]
    float bsum[16], bsq[16];
    #pragma unroll
    for (int r = 0; r < 16; r++) {
      int row = (r & 3) + 8 * (r >> 2) + 4 * lhi;
      int col = mh * 32 + row;
      float bv = cb[co0 + col];
      float s = 0.f, q = 0.f;
      #pragma unroll
      for (int nn = 0; nn < 3; nn++) {
        float y = acc[nn][r] + bv;
        int px = nn * 32 + l31;
        tbl[(rw * 96 + px) * 68 + col] = f2bf(y);
        s += y;
        q = fmaf(y, y, q);
      }
      bsum[r] = s; bsq[r] = q;
    }
    #pragma unroll
    for (int r = 0; r < 16; r++) {
      float s = bsum[r], q = bsq[r];
      #pragma unroll
      for (int off = 16; off > 0; off >>= 1) {
        s += __shfl_xor(s, off, 64);
        q += __shfl_xor(q, off, 64);
      }
      bsum[r] = s; bsq[r] = q;
    }
    if (l31 == 0) {
      float* pp = psum + ((((size_t)b * 48 + hb) * 2 + rw) * 256) * 2;
      #pragma unroll
      for (int r = 0; r < 16; r++) {
        int row = (r & 3) + 8 * (r >> 2) + 4 * lhi;
        int co = co0 + mh * 32 + row;
        pp[co * 2]     = bsum[r];
        pp[co * 2 + 1] = bsq[r];
      }
    }
    __syncthreads();
    unsigned short* dstb = xt2 + (size_t)b * XT_PLANE;
    #pragma unroll
    for (int i = 0; i < 6; i++) {
      int c = t + i * 256;
      int row2 = c / 768;
      int rem = c - row2 * 768;
      int wi = rem >> 3, p8 = rem & 7;
      const unsigned short* lsrc = &tbl[(row2 * 96 + wi) * 68 + p8 * 8];
      uint2 lo = *(const uint2*)lsrc;
      uint2 hi2 = *(const uint2*)(lsrc + 4);
      size_t ga = ((size_t)(h0 + 1 + row2) * 98 + (wi + 1)) * 256 + co0 + p8 * 8;
      uint4 vv; vv.x = lo.x; vv.y = lo.y; vv.z = hi2.x; vv.w = hi2.y;
      *(uint4*)&dstb[ga] = vv;
    }
  } else {
    // conv2: f32 plane-major output
    #pragma unroll
    for (int r = 0; r < 16; r++) {
      int row = (r & 3) + 8 * (r >> 2) + 4 * lhi;
      int co = co0 + mh * 32 + row;
      float bv = cb[co];
      size_t base = ((size_t)(b * 256 + co) * 96 + h) * 96;
      #pragma unroll
      for (int nn = 0; nn < 3; nn++) {
        out[base + nn * 32 + l31] = acc[nn][r] + bv;
      }
    }
  }
}

// ---------------------------------------------------------------------------
extern "C" void kernel_launch(void* const* d_in, const int* in_sizes, int n_in,
                              void* d_out, int out_size, void* d_ws, size_t ws_size,
                              hipStream_t stream)
{
  const float* fm    = (const float*)d_in[0];
  const float* para  = (const float*)d_in[1];
  const float* style = (const float*)d_in[2];
  const float* cw  = (const float*)d_in[3];
  const float* cb  = (const float*)d_in[4];
  const float* sw  = (const float*)d_in[5];
  const float* sb  = (const float*)d_in[6];
  const float* rw  = (const float*)d_in[7];
  const float* rb  = (const float*)d_in[8];
  const float* tw  = (const float*)d_in[9];
  const float* tb  = (const float*)d_in[10];
  const float* a1w = (const float*)d_in[11];
  const float* a1b = (const float*)d_in[12];
  const float* g1w = (const float*)d_in[13];
  const float* g1b = (const float*)d_in[14];
  const float* b1w = (const float*)d_in[15];
  const float* b1b = (const float*)d_in[16];
  const float* c1w = (const float*)d_in[17];
  const float* c1b = (const float*)d_in[18];
  const float* a2w = (const float*)d_in[19];
  const float* a2b = (const float*)d_in[20];
  const float* g2w = (const float*)d_in[21];
  const float* g2b = (const float*)d_in[22];
  const float* b2w = (const float*)d_in[23];
  const float* b2b = (const float*)d_in[24];
  const float* c2w = (const float*)d_in[25];
  const float* c2b = (const float*)d_in[26];

  float* outf = (float*)d_out;
  unsigned short* tbf16 = (unsigned short*)d_out;  // bf16 t (first half of d_out)

  unsigned short* xtbuf  = (unsigned short*)d_ws;                 // xt1
  unsigned short* xt2buf = xtbuf + (size_t)BATCH * XT_PLANE;      // xt2
  unsigned short* wf1    = xt2buf + (size_t)BATCH * XT_PLANE;
  unsigned short* wf2    = wf1 + 9 * 256 * 256;
  float* fws  = (float*)(wf2 + 9 * 256 * 256);
  float* warp = fws;                   // 4096
  float* gb1  = warp + 4 * 1024;       // 2048
  float* gb2  = gb1 + 2 * 1024;        // 2048
  float* nrm2 = gb2 + 2 * 1024;        // 2048
  float* pcbuf = nrm2 + 2 * 1024;      // 1024
  float* a1buf = pcbuf + 1024;         // 512
  float* a2buf = a1buf + 512;          // 512
  float* psum  = a2buf + 512;          // 98304 floats

  params_stage1_kernel<<<dim3(6, 4), 256, 0, stream>>>(para, style, cw, cb,
      a1w, a1b, a2w, a2b, pcbuf, a1buf, a2buf);
  params_stage2_kernel<<<dim3(16, 4), 256, 0, stream>>>(pcbuf, a1buf, a2buf,
      sw, sb, rw, rb, tw, tb, g1w, g1b, b1w, b1b, g2w, g2b, b2w, b2b,
      warp, gb1, gb2);
  prep_weights_kernel<<<512, 256, 0, stream>>>(c1w, c2w, wf1, wf2);
  adaat_kernel<<<1024, 256, 0, stream>>>(fm, warp, gb1, tbf16);
  transpose_kernel<<<dim3(98, 4), 256, 0, stream>>>(tbf16, xtbuf);
  conv_mfma_kernel<<<dim3(48, 4, 4), 256, 0, stream>>>(xtbuf, wf1, c1b,
      outf, xt2buf, psum);
  finalize_stats_kernel<<<4, 256, 0, stream>>>(psum, gb2, nrm2);
  norm2_kernel<<<dim3(98, 4), 256, 0, stream>>>(xt2buf, nrm2);
  conv_mfma_kernel<<<dim3(48, 4, 4), 256, 0, stream>>>(xt2buf, wf2, c2b,
      outf, nullptr, nullptr);
}

// Round 16
// 181.328 us; speedup vs baseline: 1.1049x; 1.1049x over previous
//
#include <hip/hip_runtime.h>
#include <hip/hip_bf16.h>
#include <cstddef>

#define BATCH 4
#define CH 256
#define HH 96
#define WW 96
#define HWN (HH*WW)               // 9216
#define NTOT (BATCH*CH*HWN)       // 9437184
#define XT_H 98
#define XT_W 98
#define XT_PLANE (XT_H*XT_W*CH)   // per-batch elements in xt (bf16)

typedef __attribute__((ext_vector_type(16))) float f32x16;
typedef __attribute__((ext_vector_type(8))) __bf16 bfrag;
typedef __attribute__((ext_vector_type(8))) unsigned short u16x8;

static __device__ __forceinline__ unsigned short f2bf(float f) {
  unsigned int u = __float_as_uint(f);
  unsigned int r = (u + 0x7fffu + ((u >> 16) & 1u)) >> 16;
  return (unsigned short)r;
}
static __device__ __forceinline__ float bf2f(unsigned short s) {
  return __uint_as_float(((unsigned int)s) << 16);
}

// async global->LDS, 16B per lane; LDS dest = wave-uniform base + lane*16
static __device__ __forceinline__ void gload16(const unsigned short* g,
                                               unsigned short* l) {
  __builtin_amdgcn_global_load_lds(
      (const __attribute__((address_space(1))) unsigned int*)g,
      (__attribute__((address_space(3))) unsigned int*)l, 16, 0, 0);
}

// ---------------------------------------------------------------------------
// Kernel 1a: stage-1 GEMVs, wide-parallel (unchanged R9).
// ---------------------------------------------------------------------------
__global__ __launch_bounds__(256) void params_stage1_kernel(
    const float* __restrict__ para, const float* __restrict__ style,
    const float* __restrict__ cw,  const float* __restrict__ cb,
    const float* __restrict__ a1w, const float* __restrict__ a1b,
    const float* __restrict__ a2w, const float* __restrict__ a2b,
    float* __restrict__ pcbuf, float* __restrict__ a1buf, float* __restrict__ a2buf)
{
  __shared__ float s_in[256];
  __shared__ float red[256];
  int part = blockIdx.x, b = blockIdx.y, t = threadIdx.x;
  s_in[t] = (part < 4) ? para[b*256 + t] : style[b*256 + t];
  __syncthreads();
  if (part < 4) {
    int o = t & 63, ks = t >> 6, co0 = part * 64;
    const float* wcol = cw + co0 + o;
    float acc = 0.f;
    #pragma unroll 8
    for (int i = 0; i < 64; i++) {
      int k = ks * 64 + i;
      acc = fmaf(s_in[k], wcol[k * 256], acc);
    }
    red[t] = acc;
    __syncthreads();
    if (t < 64) {
      float s = red[t] + red[t + 64] + red[t + 128] + red[t + 192];
      pcbuf[b*256 + co0 + t] = fmaxf(s + cb[co0 + t], 0.f);
    }
  } else {
    const float* w  = (part == 4) ? a1w : a2w;
    const float* bb = (part == 4) ? a1b : a2b;
    float* outp = (part == 4) ? a1buf : a2buf;
    int o = t & 127, ks = t >> 7;
    const float* wcol = w + o;
    float acc = 0.f;
    #pragma unroll 8
    for (int i = 0; i < 128; i++) {
      int k = ks * 128 + i;
      acc = fmaf(s_in[k], wcol[k * 128], acc);
    }
    red[t] = acc;
    __syncthreads();
    if (t < 128) {
      float s = red[t] + red[t + 128];
      outp[b*128 + t] = fmaxf(s + bb[t], 0.f);
    }
  }
}

// ---------------------------------------------------------------------------
// Kernel 1b: stage-2 params (unchanged R9).
// ---------------------------------------------------------------------------
__global__ __launch_bounds__(256) void params_stage2_kernel(
    const float* __restrict__ pcbuf, const float* __restrict__ a1buf,
    const float* __restrict__ a2buf,
    const float* __restrict__ sw,  const float* __restrict__ sb,
    const float* __restrict__ rw,  const float* __restrict__ rb,
    const float* __restrict__ tw,  const float* __restrict__ tb,
    const float* __restrict__ g1w, const float* __restrict__ g1b,
    const float* __restrict__ b1w, const float* __restrict__ b1b,
    const float* __restrict__ g2w, const float* __restrict__ g2b,
    const float* __restrict__ b2w, const float* __restrict__ b2b,
    float* __restrict__ warp, float* __restrict__ gb1, float* __restrict__ gb2)
{
  __shared__ float s_pc[256], s_a1[128], s_a2[128];
  __shared__ float red[8][4][16];
  int co0 = blockIdx.x * 16, b = blockIdx.y, t = threadIdx.x;
  s_pc[t] = pcbuf[b*256 + t];
  if (t < 128) s_a1[t] = a1buf[b*128 + t];
  else         s_a2[t - 128] = a2buf[b*128 + (t - 128)];
  __syncthreads();

  int cl = t & 15, klane = t >> 4;
  int c = co0 + cl;
  const float2* tw2 = (const float2*)tw;
  float ds = 0.f, dr = 0.f, dtx = 0.f, dty = 0.f;
  float g1 = 0.f, be1 = 0.f, g2 = 0.f, be2 = 0.f;
  #pragma unroll 4
  for (int kk = 0; kk < 16; kk++) {
    int i = klane * 16 + kk;
    float p = s_pc[i];
    ds  = fmaf(p, sw[i*256 + c], ds);
    dr  = fmaf(p, rw[i*256 + c], dr);
    float2 tv = tw2[i*256 + c];
    dtx = fmaf(p, tv.x, dtx);
    dty = fmaf(p, tv.y, dty);
  }
  #pragma unroll 4
  for (int kk = 0; kk < 8; kk++) {
    int i = klane * 8 + kk;
    float a = s_a1[i];
    g1  = fmaf(a, g1w[i*256 + c], g1);
    be1 = fmaf(a, b1w[i*256 + c], be1);
    float a2v = s_a2[i];
    g2  = fmaf(a2v, g2w[i*256 + c], g2);
    be2 = fmaf(a2v, b2w[i*256 + c], be2);
  }
  ds  += __shfl_down(ds, 32, 64);  ds  += __shfl_down(ds, 16, 64);
  dr  += __shfl_down(dr, 32, 64);  dr  += __shfl_down(dr, 16, 64);
  dtx += __shfl_down(dtx, 32, 64); dtx += __shfl_down(dtx, 16, 64);
  dty += __shfl_down(dty, 32, 64); dty += __shfl_down(dty, 16, 64);
  g1  += __shfl_down(g1, 32, 64);  g1  += __shfl_down(g1, 16, 64);
  be1 += __shfl_down(be1, 32, 64); be1 += __shfl_down(be1, 16, 64);
  g2  += __shfl_down(g2, 32, 64);  g2  += __shfl_down(g2, 16, 64);
  be2 += __shfl_down(be2, 32, 64); be2 += __shfl_down(be2, 16, 64);
  int wv = t >> 6;
  if ((t & 63) < 16) {
    red[0][wv][cl] = ds;  red[1][wv][cl] = dr;
    red[2][wv][cl] = dtx; red[3][wv][cl] = dty;
    red[4][wv][cl] = g1;  red[5][wv][cl] = be1;
    red[6][wv][cl] = g2;  red[7][wv][cl] = be2;
  }
  __syncthreads();
  if (t < 16) {
    float v[8];
    #pragma unroll
    for (int o = 0; o < 8; o++)
      v[o] = red[o][0][t] + red[o][1][t] + red[o][2][t] + red[o][3][t];
    int cc = co0 + t;
    int bc = b*256 + cc;
    float scale = 2.f / (1.f + expf(-(v[0] + sb[cc])));
    float ang = tanhf(v[1] + rb[cc]) * 3.14159f;
    float sn, cs;
    sincosf(ang, &sn, &cs);
    warp[bc*4 + 0] = cs * scale;
    warp[bc*4 + 1] = sn * scale;
    warp[bc*4 + 2] = tanhf(v[2] + tb[2*cc]);
    warp[bc*4 + 3] = tanhf(v[3] + tb[2*cc + 1]);
    gb1[bc*2]     = v[4] + g1b[cc];
    gb1[bc*2 + 1] = v[5] + b1b[cc];
    gb2[bc*2]     = v[6] + g2b[cc];
    gb2[bc*2 + 1] = v[7] + b2b[cc];
  }
}

// ---------------------------------------------------------------------------
// Kernel 2: weight preconversion (unchanged).
// wf[coblk4][ks16][tap9][m2][lane64][8]
// ---------------------------------------------------------------------------
__global__ __launch_bounds__(256) void prep_weights_kernel(
    const float* __restrict__ w1, const float* __restrict__ w2,
    unsigned short* __restrict__ wf1, unsigned short* __restrict__ wf2)
{
  int co = blockIdx.x & 255;
  const float* src = (blockIdx.x < 256) ? w1 : w2;
  unsigned short* dst = (blockIdx.x < 256) ? wf1 : wf2;
  int ci = threadIdx.x;
  int coblk = co >> 6, m = (co >> 5) & 1;
  int l = (co & 31) | (((ci >> 3) & 1) << 5);
  int ks = ci >> 4, j = ci & 7;
  const float* p = src + ((size_t)co * 256 + ci) * 9;
  #pragma unroll
  for (int tap = 0; tap < 9; tap++) {
    size_t idx = (((size_t)((coblk * 16 + ks) * 9 + tap) * 2 + m) * 64 + l) * 8 + j;
    dst[idx] = f2bf(p[tap]);
  }
}

// ---------------------------------------------------------------------------
// Kernel 3: AdaAT warp + fused stats + AdaIN-1 + lrelu + bf16 cvt (R14).
// ---------------------------------------------------------------------------
__global__ __launch_bounds__(256) void adaat_kernel(
    const float* __restrict__ fm, const float* __restrict__ warp,
    const float* __restrict__ gb1, unsigned short* __restrict__ tout)
{
  __shared__ float s[96 * 100];
  int bc = blockIdx.x;
  int b = bc >> 8, c = bc & 255;
  float csc = warp[bc*4 + 0], ssc = warp[bc*4 + 1];
  float tx = warp[bc*4 + 2], ty = warp[bc*4 + 3];

  const float axw = csc * (96.f / 95.f);
  const float axh = -ssc * (96.f / 95.f);
  const float ax0 = 48.f * (tx - csc + ssc) + 47.5f;
  const float ayw = ssc * (96.f / 95.f);
  const float ayh = csc * (96.f / 95.f);
  const float ay0 = 48.f * (ty - ssc - csc) + 47.5f;

  float iz = 256.f * (float)c / 255.f - 0.5f;
  float z0f = floorf(iz);
  float wz = iz - z0f;
  int z0 = (int)z0f;
  const float* p0 = (z0 >= 0) ? fm + (size_t)(b*256 + z0) * HWN : nullptr;
  const float* p1 = (z0 + 1 < 256) ? fm + (size_t)(b*256 + z0 + 1) * HWN : nullptr;
  float w0 = 1.f - wz, w1 = wz;

  int t = threadIdx.x;
  const float4* q0 = (const float4*)p0;
  const float4* q1 = (const float4*)p1;
  for (int i = t; i < 2304; i += 256) {
    int row = i / 24, col = i - row * 24;
    float4 r = {0.f, 0.f, 0.f, 0.f};
    if (q0) {
      float4 v = q0[i];
      r.x = w0 * v.x; r.y = w0 * v.y; r.z = w0 * v.z; r.w = w0 * v.w;
    }
    if (q1) {
      float4 v = q1[i];
      r.x = fmaf(w1, v.x, r.x); r.y = fmaf(w1, v.y, r.y);
      r.z = fmaf(w1, v.z, r.z); r.w = fmaf(w1, v.w, r.w);
    }
    *(float4*)&s[row * 100 + col * 4] = r;
  }
  __syncthreads();

  int h = t / 96, w = t - (t / 96) * 96;
  float vals[36];
  float sum = 0.f, sumsq = 0.f;
  #pragma unroll
  for (int k = 0; k < 36; k++) {
    float ix = fmaf(axw, (float)w, fmaf(axh, (float)h, ax0));
    float iy = fmaf(ayw, (float)w, fmaf(ayh, (float)h, ay0));
    float x0f = floorf(ix), y0f = floorf(iy);
    float wx = ix - x0f, wy = iy - y0f;
    int x0 = (int)x0f, y0 = (int)y0f;
    int x0c = min(max(x0, 0), 95), x1c = min(max(x0 + 1, 0), 95);
    int y0c = min(max(y0, 0), 95), y1c = min(max(y0 + 1, 0), 95);
    bool vx0 = (unsigned)x0 < 96u, vx1 = (unsigned)(x0 + 1) < 96u;
    bool vy0 = (unsigned)y0 < 96u, vy1 = (unsigned)(y0 + 1) < 96u;
    float a00 = s[y0c * 100 + x0c], a01 = s[y0c * 100 + x1c];
    float a10 = s[y1c * 100 + x0c], a11 = s[y1c * 100 + x1c];
    float wxm = 1.f - wx, wym = 1.f - wy;
    float w00 = (vy0 && vx0) ? wym * wxm : 0.f;
    float w01 = (vy0 && vx1) ? wym * wx  : 0.f;
    float w10 = (vy1 && vx0) ? wy * wxm  : 0.f;
    float w11 = (vy1 && vx1) ? wy * wx   : 0.f;
    float v = w00 * a00;
    v = fmaf(w01, a01, v);
    v = fmaf(w10, a10, v);
    v = fmaf(w11, a11, v);
    vals[k] = v;
    sum += v;
    sumsq = fmaf(v, v, sumsq);
    int wn = w + 64;
    int carry = (wn >= 96) ? 1 : 0;
    w = wn - (carry ? 96 : 0);
    h += 2 + carry;
  }

  for (int off = 32; off > 0; off >>= 1) {
    sum   += __shfl_down(sum, off, 64);
    sumsq += __shfl_down(sumsq, off, 64);
  }
  __shared__ float rs[4], rq[4], sbi[2];
  int lane = t & 63, wvi = t >> 6;
  if (lane == 0) { rs[wvi] = sum; rq[wvi] = sumsq; }
  __syncthreads();
  if (t == 0) {
    float S = rs[0] + rs[1] + rs[2] + rs[3];
    float Q = rq[0] + rq[1] + rq[2] + rq[3];
    float m = S * (1.f / 9216.f);
    float var = Q * (1.f / 9216.f) - m * m;
    float rstd = rsqrtf(var + 1e-5f);
    float sc = (1.f + gb1[bc*2]) * rstd;
    sbi[0] = sc;
    sbi[1] = gb1[bc*2 + 1] - m * sc;
  }
  __syncthreads();
  float sc = sbi[0], bi = sbi[1];
  unsigned short* dst = tout + (size_t)bc * HWN + t;
  #pragma unroll
  for (int k = 0; k < 36; k++) {
    float y = fmaf(vals[k], sc, bi);
    y = (y >= 0.f) ? y : 0.2f * y;
    dst[k * 256] = f2bf(y);
  }
}

// ---------------------------------------------------------------------------
// Kernel 4: finalize per-(b,co) stats from conv1 partials (unchanged).
// ---------------------------------------------------------------------------
__global__ __launch_bounds__(256) void finalize_stats_kernel(
    const float* __restrict__ psum, const float* __restrict__ gb,
    float* __restrict__ nrm)
{
  int bc = blockIdx.x * 256 + threadIdx.x;
  int b = bc >> 8, co = bc & 255;
  float S = 0.f, Q = 0.f;
  for (int j = 0; j < 96; j++) {
    const float* p = psum + ((((size_t)b * 48 + (j >> 1)) * 2 + (j & 1)) * 256 + co) * 2;
    S += p[0];
    Q += p[1];
  }
  float m = S * (1.f / 9216.f);
  float var = Q * (1.f / 9216.f) - m * m;
  float rstd = rsqrtf(var + 1e-5f);
  float sc = (1.f + gb[bc*2]) * rstd;
  nrm[bc*2] = sc;
  nrm[bc*2 + 1] = gb[bc*2 + 1] - m * sc;
}

// ---------------------------------------------------------------------------
// Kernel 5: pure bf16 transpose t(plane-major) -> xt layout + borders (R14).
// ---------------------------------------------------------------------------
__global__ __launch_bounds__(256) void transpose_kernel(
    const unsigned short* __restrict__ tb, unsigned short* __restrict__ xt)
{
  int hi = blockIdx.x;
  int b  = blockIdx.y;
  unsigned short* dst = xt + (size_t)b * XT_PLANE + (size_t)hi * (XT_W * CH);
  int t = threadIdx.x;
  int h = hi - 1;
  u16x8 zero = {0,0,0,0,0,0,0,0};
  if (h < 0 || h >= 96) {
    for (int c = t; c < XT_W * CH / 8; c += 256) ((u16x8*)dst)[c] = zero;
    return;
  }
  __shared__ unsigned short s[96 * 256];  // [w][ci]
  int ci = t;
  const unsigned short* src = tb + ((size_t)(b*256 + ci)) * HWN + h * 96;
  #pragma unroll
  for (int wg = 0; wg < 12; wg++) {
    u16x8 v = *(const u16x8*)(src + wg * 8);
    #pragma unroll
    for (int j = 0; j < 8; j++) s[(wg*8 + j) * 256 + ci] = v[j];
  }
  __syncthreads();
  for (int c = t; c < 98 * 32; c += 256) {
    int w = c >> 5, p = c & 31;
    u16x8 v = zero;
    if (w >= 1 && w <= 96) v = *(const u16x8*)&s[(w - 1) * 256 + p * 8];
    ((u16x8*)dst)[c] = v;
  }
}

// ---------------------------------------------------------------------------
// Kernel 5b: elementwise AdaIN-2 + lrelu on bf16 xt2, in place (unchanged).
// ---------------------------------------------------------------------------
__global__ __launch_bounds__(256) void norm2_kernel(
    unsigned short* __restrict__ xt, const float* __restrict__ nrm)
{
  int hi = blockIdx.x, b = blockIdx.y;
  unsigned short* row = xt + (size_t)b * XT_PLANE + (size_t)hi * (XT_W * CH);
  int t = threadIdx.x;
  u16x8 zero = {0,0,0,0,0,0,0,0};
  if (hi == 0 || hi == 97) {
    for (int c = t; c < XT_W * CH / 8; c += 256) ((u16x8*)row)[c] = zero;
    return;
  }
  int p = t & 31;
  float sc[8], bi[8];
  #pragma unroll
  for (int j = 0; j < 8; j++) {
    int co = p * 8 + j;
    sc[j] = nrm[(b*256 + co)*2];
    bi[j] = nrm[(b*256 + co)*2 + 1];
  }
  for (int wi = t >> 5; wi < 98; wi += 8) {
    int c = wi * 32 + p;
    if (wi == 0 || wi == 97) { ((u16x8*)row)[c] = zero; continue; }
    u16x8 v = ((u16x8*)row)[c];
    u16x8 o;
    #pragma unroll
    for (int j = 0; j < 8; j++) {
      float x = bf2f(v[j]);
      float y = fmaf(x, sc[j], bi[j]);
      y = (y >= 0.f) ? y : 0.2f * y;
      o[j] = f2bf(y);
    }
    ((u16x8*)row)[c] = o;
  }
}

// ---------------------------------------------------------------------------
// Kernel 6 (R16 = R13-exact): conv, dim3 grid, proven 62 µs main loop.
// Epilogue: conv1 writes bf16 transposed (LDS bounce) + stats partials;
// conv2 writes f32 plane-major.
// ---------------------------------------------------------------------------
__global__ __launch_bounds__(256, 3) void conv_mfma_kernel(
    const unsigned short* __restrict__ xt,   // input [4][98][98][256] bf16
    const unsigned short* __restrict__ wf,   // frag layout (see prep)
    const float* __restrict__ cb,
    float* __restrict__ out,                 // f32 output (conv2 path)
    unsigned short* __restrict__ xt2,        // bf16 transposed output (conv1)
    float* __restrict__ psum)                // partials or nullptr
{
  __shared__ __align__(16) unsigned short s_in[2][6528];

  int hb = blockIdx.x, coblk = blockIdx.y, b = blockIdx.z;
  int co0 = coblk * 64, h0 = hb * 2;
  int t = threadIdx.x, lane = t & 63, wv = t >> 6;
  int rw = wv >> 1, mh = wv & 1;
  int l31 = lane & 31, lhi = lane >> 5;
  const unsigned short* xtb = xt + (size_t)b * XT_PLANE;

  int pre_g[4];
  #pragma unroll
  for (int i = 0; i < 4; i++) {
    int c = t + i * 256;
    if (c < 784) {
      int r = c / 196;
      int rem = c - r * 196;
      int half = rem / 98;
      int w = rem - half * 98;
      pre_g[i] = ((h0 + r) * 98 + w) * 256 + half * 8;
    }
  }

  f32x16 acc[3];
  #pragma unroll
  for (int nn = 0; nn < 3; nn++)
    #pragma unroll
    for (int i = 0; i < 16; i++) acc[nn][i] = 0.f;

  const unsigned short* wfb = wf + (size_t)(coblk * 16) * 9216 + mh * 512 + lane * 8;

  {
    #pragma unroll
    for (int i = 0; i < 3; i++)
      gload16(xtb + pre_g[i], &s_in[0][(i * 256 + wv * 64) * 8]);
    u16x8 tail0;
    if (t < 16) tail0 = *(const u16x8*)(xtb + pre_g[3]);
    if (t < 16) *(u16x8*)(&s_in[0][(768 + t) * 8]) = tail0;
  }
  bfrag wa[9];
  #pragma unroll
  for (int tap = 0; tap < 9; tap++) wa[tap] = *(const bfrag*)(wfb + tap * 1024);
  __syncthreads();

  int buf = 0;
  u16x8 tail;
  #pragma unroll 1
  for (int ks = 0; ks < 16; ks++) {
    if (ks < 15) {
      int cib = (ks + 1) * 16;
      unsigned short* nb = s_in[buf ^ 1];
      #pragma unroll
      for (int i = 0; i < 3; i++)
        gload16(xtb + pre_g[i] + cib, &nb[(i * 256 + wv * 64) * 8]);
      if (t < 16) tail = *(const u16x8*)(xtb + pre_g[3] + cib);
    }
    const unsigned short* sb = s_in[buf];
    int ksn = (ks < 15) ? (ks + 1) : 15;
    const unsigned short* wkn = wfb + (size_t)ksn * 9216;
    #pragma unroll
    for (int ky = 0; ky < 3; ky++) {
      const unsigned short* srow = sb + (((rw + ky) * 2 + lhi) * 98) * 8;
      bfrag bb[9];
      #pragma unroll
      for (int kx = 0; kx < 3; kx++)
        #pragma unroll
        for (int nn = 0; nn < 3; nn++)
          bb[kx * 3 + nn] = *(const bfrag*)(srow + (nn * 32 + kx + l31) * 8);
      __builtin_amdgcn_s_setprio(1);
      #pragma unroll
      for (int kx = 0; kx < 3; kx++) {
        int tap = ky * 3 + kx;
        acc[0] = __builtin_amdgcn_mfma_f32_32x32x16_bf16(wa[tap], bb[kx*3+0], acc[0], 0, 0, 0);
        acc[1] = __builtin_amdgcn_mfma_f32_32x32x16_bf16(wa[tap], bb[kx*3+1], acc[1], 0, 0, 0);
        acc[2] = __builtin_amdgcn_mfma_f32_32x32x16_bf16(wa[tap], bb[kx*3+2], acc[2], 0, 0, 0);
        wa[tap] = *(const bfrag*)(wkn + tap * 1024);
      }
      __builtin_amdgcn_s_setprio(0);
    }
    if (ks < 15 && t < 16) *(u16x8*)(&s_in[buf ^ 1][(768 + t) * 8]) = tail;
    __syncthreads();
    buf ^= 1;
  }

  int h = h0 + rw;
  if (psum) {
    // conv1: bf16 transposed output via LDS bounce + stats partials
    unsigned short* tbl = (unsigned short*)s_in;   // [2 rows][96 px][68 co-pad]
    float bsum[16], bsq[16];
    #pragma unroll
    for (int r = 0; r < 16; r++) {
      int row = (r & 3) + 8 * (r >> 2) + 4 * lhi;
      int col = mh * 32 + row;
      float bv = cb[co0 + col];
      float s = 0.f, q = 0.f;
      #pragma unroll
      for (int nn = 0; nn < 3; nn++) {
        float y = acc[nn][r] + bv;
        int px = nn * 32 + l31;
        tbl[(rw * 96 + px) * 68 + col] = f2bf(y);
        s += y;
        q = fmaf(y, y, q);
      }
      bsum[r] = s; bsq[r] = q;
    }
    #pragma unroll
    for (int r = 0; r < 16; r++) {
      float s = bsum[r], q = bsq[r];
      #pragma unroll
      for (int off = 16; off > 0; off >>= 1) {
        s += __shfl_xor(s, off, 64);
        q += __shfl_xor(q, off, 64);
      }
      bsum[r] = s; bsq[r] = q;
    }
    if (l31 == 0) {
      float* pp = psum + ((((size_t)b * 48 + hb) * 2 + rw) * 256) * 2;
      #pragma unroll
      for (int r = 0; r < 16; r++) {
        int row = (r & 3) + 8 * (r >> 2) + 4 * lhi;
        int co = co0 + mh * 32 + row;
        pp[co * 2]     = bsum[r];
        pp[co * 2 + 1] = bsq[r];
      }
    }
    __syncthreads();
    unsigned short* dstb = xt2 + (size_t)b * XT_PLANE;
    #pragma unroll
    for (int i = 0; i < 6; i++) {
      int c = t + i * 256;
      int row2 = c / 768;
      int rem = c - row2 * 768;
      int wi = rem >> 3, p8 = rem & 7;
      const unsigned short* lsrc = &tbl[(row2 * 96 + wi) * 68 + p8 * 8];
      uint2 lo = *(const uint2*)lsrc;
      uint2 hi2 = *(const uint2*)(lsrc + 4);
      size_t ga = ((size_t)(h0 + 1 + row2) * 98 + (wi + 1)) * 256 + co0 + p8 * 8;
      uint4 vv; vv.x = lo.x; vv.y = lo.y; vv.z = hi2.x; vv.w = hi2.y;
      *(uint4*)&dstb[ga] = vv;
    }
  } else {
    // conv2: f32 plane-major output
    #pragma unroll
    for (int r = 0; r < 16; r++) {
      int row = (r & 3) + 8 * (r >> 2) + 4 * lhi;
      int co = co0 + mh * 32 + row;
      float bv = cb[co];
      size_t base = ((size_t)(b * 256 + co) * 96 + h) * 96;
      #pragma unroll
      for (int nn = 0; nn < 3; nn++) {
        out[base + nn * 32 + l31] = acc[nn][r] + bv;
      }
    }
  }
}

// ---------------------------------------------------------------------------
extern "C" void kernel_launch(void* const* d_in, const int* in_sizes, int n_in,
                              void* d_out, int out_size, void* d_ws, size_t ws_size,
                              hipStream_t stream)
{
  const float* fm    = (const float*)d_in[0];
  const float* para  = (const float*)d_in[1];
  const float* style = (const float*)d_in[2];
  const float* cw  = (const float*)d_in[3];
  const float* cb  = (const float*)d_in[4];
  const float* sw  = (const float*)d_in[5];
  const float* sb  = (const float*)d_in[6];
  const float* rw  = (const float*)d_in[7];
  const float* rb  = (const float*)d_in[8];
  const float* tw  = (const float*)d_in[9];
  const float* tb  = (const float*)d_in[10];
  const float* a1w = (const float*)d_in[11];
  const float* a1b = (const float*)d_in[12];
  const float* g1w = (const float*)d_in[13];
  const float* g1b = (const float*)d_in[14];
  const float* b1w = (const float*)d_in[15];
  const float* b1b = (const float*)d_in[16];
  const float* c1w = (const float*)d_in[17];
  const float* c1b = (const float*)d_in[18];
  const float* a2w = (const float*)d_in[19];
  const float* a2b = (const float*)d_in[20];
  const float* g2w = (const float*)d_in[21];
  const float* g2b = (const float*)d_in[22];
  const float* b2w = (const float*)d_in[23];
  const float* b2b = (const float*)d_in[24];
  const float* c2w = (const float*)d_in[25];
  const float* c2b = (const float*)d_in[26];

  float* outf = (float*)d_out;
  unsigned short* tbf16 = (unsigned short*)d_out;  // bf16 t (first half of d_out)

  unsigned short* xtbuf  = (unsigned short*)d_ws;                 // xt1
  unsigned short* xt2buf = xtbuf + (size_t)BATCH * XT_PLANE;      // xt2
  unsigned short* wf1    = xt2buf + (size_t)BATCH * XT_PLANE;
  unsigned short* wf2    = wf1 + 9 * 256 * 256;
  float* fws  = (float*)(wf2 + 9 * 256 * 256);
  float* warp = fws;                   // 4096
  float* gb1  = warp + 4 * 1024;       // 2048
  float* gb2  = gb1 + 2 * 1024;        // 2048
  float* nrm2 = gb2 + 2 * 1024;        // 2048
  float* pcbuf = nrm2 + 2 * 1024;      // 1024
  float* a1buf = pcbuf + 1024;         // 512
  float* a2buf = a1buf + 512;          // 512
  float* psum  = a2buf + 512;          // 98304 floats

  params_stage1_kernel<<<dim3(6, 4), 256, 0, stream>>>(para, style, cw, cb,
      a1w, a1b, a2w, a2b, pcbuf, a1buf, a2buf);
  params_stage2_kernel<<<dim3(16, 4), 256, 0, stream>>>(pcbuf, a1buf, a2buf,
      sw, sb, rw, rb, tw, tb, g1w, g1b, b1w, b1b, g2w, g2b, b2w, b2b,
      warp, gb1, gb2);
  prep_weights_kernel<<<512, 256, 0, stream>>>(c1w, c2w, wf1, wf2);
  adaat_kernel<<<1024, 256, 0, stream>>>(fm, warp, gb1, tbf16);
  transpose_kernel<<<dim3(98, 4), 256, 0, stream>>>(tbf16, xtbuf);
  conv_mfma_kernel<<<dim3(48, 4, 4), 256, 0, stream>>>(xtbuf, wf1, c1b,
      outf, xt2buf, psum);
  finalize_stats_kernel<<<4, 256, 0, stream>>>(psum, gb2, nrm2);
  norm2_kernel<<<dim3(98, 4), 256, 0, stream>>>(xt2buf, nrm2);
  conv_mfma_kernel<<<dim3(48, 4, 4), 256, 0, stream>>>(xt2buf, wf2, c2b,
      outf, nullptr, nullptr);
}

// Round 17
// 179.568 us; speedup vs baseline: 1.1158x; 1.0098x over previous
//
#include <hip/hip_runtime.h>
#include <hip/hip_bf16.h>
#include <cstddef>

#define BATCH 4
#define CH 256
#define HH 96
#define WW 96
#define HWN (HH*WW)               // 9216
#define NTOT (BATCH*CH*HWN)       // 9437184
#define XT_H 98
#define XT_W 98
#define XT_PLANE (XT_H*XT_W*CH)   // per-batch elements in xt (bf16)

typedef __attribute__((ext_vector_type(16))) float f32x16;
typedef __attribute__((ext_vector_type(8))) __bf16 bfrag;
typedef __attribute__((ext_vector_type(8))) unsigned short u16x8;

static __device__ __forceinline__ unsigned short f2bf(float f) {
  unsigned int u = __float_as_uint(f);
  unsigned int r = (u + 0x7fffu + ((u >> 16) & 1u)) >> 16;
  return (unsigned short)r;
}
static __device__ __forceinline__ float bf2f(unsigned short s) {
  return __uint_as_float(((unsigned int)s) << 16);
}

// async global->LDS, 16B per lane; LDS dest = wave-uniform base + lane*16
static __device__ __forceinline__ void gload16(const unsigned short* g,
                                               unsigned short* l) {
  __builtin_amdgcn_global_load_lds(
      (const __attribute__((address_space(1))) unsigned int*)g,
      (__attribute__((address_space(3))) unsigned int*)l, 16, 0, 0);
}

// ---------------------------------------------------------------------------
// Kernel 1a: stage-1 GEMVs, wide-parallel (unchanged R9).
// ---------------------------------------------------------------------------
__global__ __launch_bounds__(256) void params_stage1_kernel(
    const float* __restrict__ para, const float* __restrict__ style,
    const float* __restrict__ cw,  const float* __restrict__ cb,
    const float* __restrict__ a1w, const float* __restrict__ a1b,
    const float* __restrict__ a2w, const float* __restrict__ a2b,
    float* __restrict__ pcbuf, float* __restrict__ a1buf, float* __restrict__ a2buf)
{
  __shared__ float s_in[256];
  __shared__ float red[256];
  int part = blockIdx.x, b = blockIdx.y, t = threadIdx.x;
  s_in[t] = (part < 4) ? para[b*256 + t] : style[b*256 + t];
  __syncthreads();
  if (part < 4) {
    int o = t & 63, ks = t >> 6, co0 = part * 64;
    const float* wcol = cw + co0 + o;
    float acc = 0.f;
    #pragma unroll 8
    for (int i = 0; i < 64; i++) {
      int k = ks * 64 + i;
      acc = fmaf(s_in[k], wcol[k * 256], acc);
    }
    red[t] = acc;
    __syncthreads();
    if (t < 64) {
      float s = red[t] + red[t + 64] + red[t + 128] + red[t + 192];
      pcbuf[b*256 + co0 + t] = fmaxf(s + cb[co0 + t], 0.f);
    }
  } else {
    const float* w  = (part == 4) ? a1w : a2w;
    const float* bb = (part == 4) ? a1b : a2b;
    float* outp = (part == 4) ? a1buf : a2buf;
    int o = t & 127, ks = t >> 7;
    const float* wcol = w + o;
    float acc = 0.f;
    #pragma unroll 8
    for (int i = 0; i < 128; i++) {
      int k = ks * 128 + i;
      acc = fmaf(s_in[k], wcol[k * 128], acc);
    }
    red[t] = acc;
    __syncthreads();
    if (t < 128) {
      float s = red[t] + red[t + 128];
      outp[b*128 + t] = fmaxf(s + bb[t], 0.f);
    }
  }
}

// ---------------------------------------------------------------------------
// Kernel 1b: stage-2 params (unchanged R9).
// ---------------------------------------------------------------------------
__global__ __launch_bounds__(256) void params_stage2_kernel(
    const float* __restrict__ pcbuf, const float* __restrict__ a1buf,
    const float* __restrict__ a2buf,
    const float* __restrict__ sw,  const float* __restrict__ sb,
    const float* __restrict__ rw,  const float* __restrict__ rb,
    const float* __restrict__ tw,  const float* __restrict__ tb,
    const float* __restrict__ g1w, const float* __restrict__ g1b,
    const float* __restrict__ b1w, const float* __restrict__ b1b,
    const float* __restrict__ g2w, const float* __restrict__ g2b,
    const float* __restrict__ b2w, const float* __restrict__ b2b,
    float* __restrict__ warp, float* __restrict__ gb1, float* __restrict__ gb2)
{
  __shared__ float s_pc[256], s_a1[128], s_a2[128];
  __shared__ float red[8][4][16];
  int co0 = blockIdx.x * 16, b = blockIdx.y, t = threadIdx.x;
  s_pc[t] = pcbuf[b*256 + t];
  if (t < 128) s_a1[t] = a1buf[b*128 + t];
  else         s_a2[t - 128] = a2buf[b*128 + (t - 128)];
  __syncthreads();

  int cl = t & 15, klane = t >> 4;
  int c = co0 + cl;
  const float2* tw2 = (const float2*)tw;
  float ds = 0.f, dr = 0.f, dtx = 0.f, dty = 0.f;
  float g1 = 0.f, be1 = 0.f, g2 = 0.f, be2 = 0.f;
  #pragma unroll 4
  for (int kk = 0; kk < 16; kk++) {
    int i = klane * 16 + kk;
    float p = s_pc[i];
    ds  = fmaf(p, sw[i*256 + c], ds);
    dr  = fmaf(p, rw[i*256 + c], dr);
    float2 tv = tw2[i*256 + c];
    dtx = fmaf(p, tv.x, dtx);
    dty = fmaf(p, tv.y, dty);
  }
  #pragma unroll 4
  for (int kk = 0; kk < 8; kk++) {
    int i = klane * 8 + kk;
    float a = s_a1[i];
    g1  = fmaf(a, g1w[i*256 + c], g1);
    be1 = fmaf(a, b1w[i*256 + c], be1);
    float a2v = s_a2[i];
    g2  = fmaf(a2v, g2w[i*256 + c], g2);
    be2 = fmaf(a2v, b2w[i*256 + c], be2);
  }
  ds  += __shfl_down(ds, 32, 64);  ds  += __shfl_down(ds, 16, 64);
  dr  += __shfl_down(dr, 32, 64);  dr  += __shfl_down(dr, 16, 64);
  dtx += __shfl_down(dtx, 32, 64); dtx += __shfl_down(dtx, 16, 64);
  dty += __shfl_down(dty, 32, 64); dty += __shfl_down(dty, 16, 64);
  g1  += __shfl_down(g1, 32, 64);  g1  += __shfl_down(g1, 16, 64);
  be1 += __shfl_down(be1, 32, 64); be1 += __shfl_down(be1, 16, 64);
  g2  += __shfl_down(g2, 32, 64);  g2  += __shfl_down(g2, 16, 64);
  be2 += __shfl_down(be2, 32, 64); be2 += __shfl_down(be2, 16, 64);
  int wv = t >> 6;
  if ((t & 63) < 16) {
    red[0][wv][cl] = ds;  red[1][wv][cl] = dr;
    red[2][wv][cl] = dtx; red[3][wv][cl] = dty;
    red[4][wv][cl] = g1;  red[5][wv][cl] = be1;
    red[6][wv][cl] = g2;  red[7][wv][cl] = be2;
  }
  __syncthreads();
  if (t < 16) {
    float v[8];
    #pragma unroll
    for (int o = 0; o < 8; o++)
      v[o] = red[o][0][t] + red[o][1][t] + red[o][2][t] + red[o][3][t];
    int cc = co0 + t;
    int bc = b*256 + cc;
    float scale = 2.f / (1.f + expf(-(v[0] + sb[cc])));
    float ang = tanhf(v[1] + rb[cc]) * 3.14159f;
    float sn, cs;
    sincosf(ang, &sn, &cs);
    warp[bc*4 + 0] = cs * scale;
    warp[bc*4 + 1] = sn * scale;
    warp[bc*4 + 2] = tanhf(v[2] + tb[2*cc]);
    warp[bc*4 + 3] = tanhf(v[3] + tb[2*cc + 1]);
    gb1[bc*2]     = v[4] + g1b[cc];
    gb1[bc*2 + 1] = v[5] + b1b[cc];
    gb2[bc*2]     = v[6] + g2b[cc];
    gb2[bc*2 + 1] = v[7] + b2b[cc];
  }
}

// ---------------------------------------------------------------------------
// Kernel 2: weight preconversion (unchanged).
// wf[coblk4][ks16][tap9][m2][lane64][8]
// ---------------------------------------------------------------------------
__global__ __launch_bounds__(256) void prep_weights_kernel(
    const float* __restrict__ w1, const float* __restrict__ w2,
    unsigned short* __restrict__ wf1, unsigned short* __restrict__ wf2)
{
  int co = blockIdx.x & 255;
  const float* src = (blockIdx.x < 256) ? w1 : w2;
  unsigned short* dst = (blockIdx.x < 256) ? wf1 : wf2;
  int ci = threadIdx.x;
  int coblk = co >> 6, m = (co >> 5) & 1;
  int l = (co & 31) | (((ci >> 3) & 1) << 5);
  int ks = ci >> 4, j = ci & 7;
  const float* p = src + ((size_t)co * 256 + ci) * 9;
  #pragma unroll
  for (int tap = 0; tap < 9; tap++) {
    size_t idx = (((size_t)((coblk * 16 + ks) * 9 + tap) * 2 + m) * 64 + l) * 8 + j;
    dst[idx] = f2bf(p[tap]);
  }
}

// ---------------------------------------------------------------------------
// Kernel 3: AdaAT warp + fused stats + AdaIN-1 + lrelu + bf16 cvt (R14).
// ---------------------------------------------------------------------------
__global__ __launch_bounds__(256) void adaat_kernel(
    const float* __restrict__ fm, const float* __restrict__ warp,
    const float* __restrict__ gb1, unsigned short* __restrict__ tout)
{
  __shared__ float s[96 * 100];
  int bc = blockIdx.x;
  int b = bc >> 8, c = bc & 255;
  float csc = warp[bc*4 + 0], ssc = warp[bc*4 + 1];
  float tx = warp[bc*4 + 2], ty = warp[bc*4 + 3];

  const float axw = csc * (96.f / 95.f);
  const float axh = -ssc * (96.f / 95.f);
  const float ax0 = 48.f * (tx - csc + ssc) + 47.5f;
  const float ayw = ssc * (96.f / 95.f);
  const float ayh = csc * (96.f / 95.f);
  const float ay0 = 48.f * (ty - ssc - csc) + 47.5f;

  float iz = 256.f * (float)c / 255.f - 0.5f;
  float z0f = floorf(iz);
  float wz = iz - z0f;
  int z0 = (int)z0f;
  const float* p0 = (z0 >= 0) ? fm + (size_t)(b*256 + z0) * HWN : nullptr;
  const float* p1 = (z0 + 1 < 256) ? fm + (size_t)(b*256 + z0 + 1) * HWN : nullptr;
  float w0 = 1.f - wz, w1 = wz;

  int t = threadIdx.x;
  const float4* q0 = (const float4*)p0;
  const float4* q1 = (const float4*)p1;
  for (int i = t; i < 2304; i += 256) {
    int row = i / 24, col = i - row * 24;
    float4 r = {0.f, 0.f, 0.f, 0.f};
    if (q0) {
      float4 v = q0[i];
      r.x = w0 * v.x; r.y = w0 * v.y; r.z = w0 * v.z; r.w = w0 * v.w;
    }
    if (q1) {
      float4 v = q1[i];
      r.x = fmaf(w1, v.x, r.x); r.y = fmaf(w1, v.y, r.y);
      r.z = fmaf(w1, v.z, r.z); r.w = fmaf(w1, v.w, r.w);
    }
    *(float4*)&s[row * 100 + col * 4] = r;
  }
  __syncthreads();

  int h = t / 96, w = t - (t / 96) * 96;
  float vals[36];
  float sum = 0.f, sumsq = 0.f;
  #pragma unroll
  for (int k = 0; k < 36; k++) {
    float ix = fmaf(axw, (float)w, fmaf(axh, (float)h, ax0));
    float iy = fmaf(ayw, (float)w, fmaf(ayh, (float)h, ay0));
    float x0f = floorf(ix), y0f = floorf(iy);
    float wx = ix - x0f, wy = iy - y0f;
    int x0 = (int)x0f, y0 = (int)y0f;
    int x0c = min(max(x0, 0), 95), x1c = min(max(x0 + 1, 0), 95);
    int y0c = min(max(y0, 0), 95), y1c = min(max(y0 + 1, 0), 95);
    bool vx0 = (unsigned)x0 < 96u, vx1 = (unsigned)(x0 + 1) < 96u;
    bool vy0 = (unsigned)y0 < 96u, vy1 = (unsigned)(y0 + 1) < 96u;
    float a00 = s[y0c * 100 + x0c], a01 = s[y0c * 100 + x1c];
    float a10 = s[y1c * 100 + x0c], a11 = s[y1c * 100 + x1c];
    float wxm = 1.f - wx, wym = 1.f - wy;
    float w00 = (vy0 && vx0) ? wym * wxm : 0.f;
    float w01 = (vy0 && vx1) ? wym * wx  : 0.f;
    float w10 = (vy1 && vx0) ? wy * wxm  : 0.f;
    float w11 = (vy1 && vx1) ? wy * wx   : 0.f;
    float v = w00 * a00;
    v = fmaf(w01, a01, v);
    v = fmaf(w10, a10, v);
    v = fmaf(w11, a11, v);
    vals[k] = v;
    sum += v;
    sumsq = fmaf(v, v, sumsq);
    int wn = w + 64;
    int carry = (wn >= 96) ? 1 : 0;
    w = wn - (carry ? 96 : 0);
    h += 2 + carry;
  }

  for (int off = 32; off > 0; off >>= 1) {
    sum   += __shfl_down(sum, off, 64);
    sumsq += __shfl_down(sumsq, off, 64);
  }
  __shared__ float rs[4], rq[4], sbi[2];
  int lane = t & 63, wvi = t >> 6;
  if (lane == 0) { rs[wvi] = sum; rq[wvi] = sumsq; }
  __syncthreads();
  if (t == 0) {
    float S = rs[0] + rs[1] + rs[2] + rs[3];
    float Q = rq[0] + rq[1] + rq[2] + rq[3];
    float m = S * (1.f / 9216.f);
    float var = Q * (1.f / 9216.f) - m * m;
    float rstd = rsqrtf(var + 1e-5f);
    float sc = (1.f + gb1[bc*2]) * rstd;
    sbi[0] = sc;
    sbi[1] = gb1[bc*2 + 1] - m * sc;
  }
  __syncthreads();
  float sc = sbi[0], bi = sbi[1];
  unsigned short* dst = tout + (size_t)bc * HWN + t;
  #pragma unroll
  for (int k = 0; k < 36; k++) {
    float y = fmaf(vals[k], sc, bi);
    y = (y >= 0.f) ? y : 0.2f * y;
    dst[k * 256] = f2bf(y);
  }
}

// ---------------------------------------------------------------------------
// Kernel 4: finalize per-(b,co) stats from conv1 partials (unchanged).
// ---------------------------------------------------------------------------
__global__ __launch_bounds__(256) void finalize_stats_kernel(
    const float* __restrict__ psum, const float* __restrict__ gb,
    float* __restrict__ nrm)
{
  int bc = blockIdx.x * 256 + threadIdx.x;
  int b = bc >> 8, co = bc & 255;
  float S = 0.f, Q = 0.f;
  for (int j = 0; j < 96; j++) {
    const float* p = psum + ((((size_t)b * 48 + (j >> 1)) * 2 + (j & 1)) * 256 + co) * 2;
    S += p[0];
    Q += p[1];
  }
  float m = S * (1.f / 9216.f);
  float var = Q * (1.f / 9216.f) - m * m;
  float rstd = rsqrtf(var + 1e-5f);
  float sc = (1.f + gb[bc*2]) * rstd;
  nrm[bc*2] = sc;
  nrm[bc*2 + 1] = gb[bc*2 + 1] - m * sc;
}

// ---------------------------------------------------------------------------
// Kernel 5: pure bf16 transpose t(plane-major) -> xt layout + borders (R14).
// ---------------------------------------------------------------------------
__global__ __launch_bounds__(256) void transpose_kernel(
    const unsigned short* __restrict__ tb, unsigned short* __restrict__ xt)
{
  int hi = blockIdx.x;
  int b  = blockIdx.y;
  unsigned short* dst = xt + (size_t)b * XT_PLANE + (size_t)hi * (XT_W * CH);
  int t = threadIdx.x;
  int h = hi - 1;
  u16x8 zero = {0,0,0,0,0,0,0,0};
  if (h < 0 || h >= 96) {
    for (int c = t; c < XT_W * CH / 8; c += 256) ((u16x8*)dst)[c] = zero;
    return;
  }
  __shared__ unsigned short s[96 * 256];  // [w][ci]
  int ci = t;
  const unsigned short* src = tb + ((size_t)(b*256 + ci)) * HWN + h * 96;
  #pragma unroll
  for (int wg = 0; wg < 12; wg++) {
    u16x8 v = *(const u16x8*)(src + wg * 8);
    #pragma unroll
    for (int j = 0; j < 8; j++) s[(wg*8 + j) * 256 + ci] = v[j];
  }
  __syncthreads();
  for (int c = t; c < 98 * 32; c += 256) {
    int w = c >> 5, p = c & 31;
    u16x8 v = zero;
    if (w >= 1 && w <= 96) v = *(const u16x8*)&s[(w - 1) * 256 + p * 8];
    ((u16x8*)dst)[c] = v;
  }
}

// ---------------------------------------------------------------------------
// Kernel 5b: elementwise AdaIN-2 + lrelu on bf16 xt2, in place (unchanged).
// ---------------------------------------------------------------------------
__global__ __launch_bounds__(256) void norm2_kernel(
    unsigned short* __restrict__ xt, const float* __restrict__ nrm)
{
  int hi = blockIdx.x, b = blockIdx.y;
  unsigned short* row = xt + (size_t)b * XT_PLANE + (size_t)hi * (XT_W * CH);
  int t = threadIdx.x;
  u16x8 zero = {0,0,0,0,0,0,0,0};
  if (hi == 0 || hi == 97) {
    for (int c = t; c < XT_W * CH / 8; c += 256) ((u16x8*)row)[c] = zero;
    return;
  }
  int p = t & 31;
  float sc[8], bi[8];
  #pragma unroll
  for (int j = 0; j < 8; j++) {
    int co = p * 8 + j;
    sc[j] = nrm[(b*256 + co)*2];
    bi[j] = nrm[(b*256 + co)*2 + 1];
  }
  for (int wi = t >> 5; wi < 98; wi += 8) {
    int c = wi * 32 + p;
    if (wi == 0 || wi == 97) { ((u16x8*)row)[c] = zero; continue; }
    u16x8 v = ((u16x8*)row)[c];
    u16x8 o;
    #pragma unroll
    for (int j = 0; j < 8; j++) {
      float x = bf2f(v[j]);
      float y = fmaf(x, sc[j], bi[j]);
      y = (y >= 0.f) ? y : 0.2f * y;
      o[j] = f2bf(y);
    }
    ((u16x8*)row)[c] = o;
  }
}

// ---------------------------------------------------------------------------
// Kernel 6 (R17): R16-exact conv main loop, setprio REMOVED (m190: setprio
// hurts lockstep barrier-synced blocks; was never isolated here).
// ---------------------------------------------------------------------------
__global__ __launch_bounds__(256, 3) void conv_mfma_kernel(
    const unsigned short* __restrict__ xt,   // input [4][98][98][256] bf16
    const unsigned short* __restrict__ wf,   // frag layout (see prep)
    const float* __restrict__ cb,
    float* __restrict__ out,                 // f32 output (conv2 path)
    unsigned short* __restrict__ xt2,        // bf16 transposed output (conv1)
    float* __restrict__ psum)                // partials or nullptr
{
  __shared__ __align__(16) unsigned short s_in[2][6528];

  int hb = blockIdx.x, coblk = blockIdx.y, b = blockIdx.z;
  int co0 = coblk * 64, h0 = hb * 2;
  int t = threadIdx.x, lane = t & 63, wv = t >> 6;
  int rw = wv >> 1, mh = wv & 1;
  int l31 = lane & 31, lhi = lane >> 5;
  const unsigned short* xtb = xt + (size_t)b * XT_PLANE;

  int pre_g[4];
  #pragma unroll
  for (int i = 0; i < 4; i++) {
    int c = t + i * 256;
    if (c < 784) {
      int r = c / 196;
      int rem = c - r * 196;
      int half = rem / 98;
      int w = rem - half * 98;
      pre_g[i] = ((h0 + r) * 98 + w) * 256 + half * 8;
    }
  }

  f32x16 acc[3];
  #pragma unroll
  for (int nn = 0; nn < 3; nn++)
    #pragma unroll
    for (int i = 0; i < 16; i++) acc[nn][i] = 0.f;

  const unsigned short* wfb = wf + (size_t)(coblk * 16) * 9216 + mh * 512 + lane * 8;

  {
    #pragma unroll
    for (int i = 0; i < 3; i++)
      gload16(xtb + pre_g[i], &s_in[0][(i * 256 + wv * 64) * 8]);
    u16x8 tail0;
    if (t < 16) tail0 = *(const u16x8*)(xtb + pre_g[3]);
    if (t < 16) *(u16x8*)(&s_in[0][(768 + t) * 8]) = tail0;
  }
  bfrag wa[9];
  #pragma unroll
  for (int tap = 0; tap < 9; tap++) wa[tap] = *(const bfrag*)(wfb + tap * 1024);
  __syncthreads();

  int buf = 0;
  u16x8 tail;
  #pragma unroll 1
  for (int ks = 0; ks < 16; ks++) {
    if (ks < 15) {
      int cib = (ks + 1) * 16;
      unsigned short* nb = s_in[buf ^ 1];
      #pragma unroll
      for (int i = 0; i < 3; i++)
        gload16(xtb + pre_g[i] + cib, &nb[(i * 256 + wv * 64) * 8]);
      if (t < 16) tail = *(const u16x8*)(xtb + pre_g[3] + cib);
    }
    const unsigned short* sb = s_in[buf];
    int ksn = (ks < 15) ? (ks + 1) : 15;
    const unsigned short* wkn = wfb + (size_t)ksn * 9216;
    #pragma unroll
    for (int ky = 0; ky < 3; ky++) {
      const unsigned short* srow = sb + (((rw + ky) * 2 + lhi) * 98) * 8;
      bfrag bb[9];
      #pragma unroll
      for (int kx = 0; kx < 3; kx++)
        #pragma unroll
        for (int nn = 0; nn < 3; nn++)
          bb[kx * 3 + nn] = *(const bfrag*)(srow + (nn * 32 + kx + l31) * 8);
      #pragma unroll
      for (int kx = 0; kx < 3; kx++) {
        int tap = ky * 3 + kx;
        acc[0] = __builtin_amdgcn_mfma_f32_32x32x16_bf16(wa[tap], bb[kx*3+0], acc[0], 0, 0, 0);
        acc[1] = __builtin_amdgcn_mfma_f32_32x32x16_bf16(wa[tap], bb[kx*3+1], acc[1], 0, 0, 0);
        acc[2] = __builtin_amdgcn_mfma_f32_32x32x16_bf16(wa[tap], bb[kx*3+2], acc[2], 0, 0, 0);
        wa[tap] = *(const bfrag*)(wkn + tap * 1024);
      }
    }
    if (ks < 15 && t < 16) *(u16x8*)(&s_in[buf ^ 1][(768 + t) * 8]) = tail;
    __syncthreads();
    buf ^= 1;
  }

  int h = h0 + rw;
  if (psum) {
    // conv1: bf16 transposed output via LDS bounce + stats partials
    unsigned short* tbl = (unsigned short*)s_in;   // [2 rows][96 px][68 co-pad]
    float bsum[16], bsq[16];
    #pragma unroll
    for (int r = 0; r < 16; r++) {
      int row = (r & 3) + 8 * (r >> 2) + 4 * lhi;
      int col = mh * 32 + row;
      float bv = cb[co0 + col];
      float s = 0.f, q = 0.f;
      #pragma unroll
      for (int nn = 0; nn < 3; nn++) {
        float y = acc[nn][r] + bv;
        int px = nn * 32 + l31;
        tbl[(rw * 96 + px) * 68 + col] = f2bf(y);
        s += y;
        q = fmaf(y, y, q);
      }
      bsum[r] = s; bsq[r] = q;
    }
    #pragma unroll
    for (int r = 0; r < 16; r++) {
      float s = bsum[r], q = bsq[r];
      #pragma unroll
      for (int off = 16; off > 0; off >>= 1) {
        s += __shfl_xor(s, off, 64);
        q += __shfl_xor(q, off, 64);
      }
      bsum[r] = s; bsq[r] = q;
    }
    if (l31 == 0) {
      float* pp = psum + ((((size_t)b * 48 + hb) * 2 + rw) * 256) * 2;
      #pragma unroll
      for (int r = 0; r < 16; r++) {
        int row = (r & 3) + 8 * (r >> 2) + 4 * lhi;
        int co = co0 + mh * 32 + row;
        pp[co * 2]     = bsum[r];
        pp[co * 2 + 1] = bsq[r];
      }
    }
    __syncthreads();
    unsigned short* dstb = xt2 + (size_t)b * XT_PLANE;
    #pragma unroll
    for (int i = 0; i < 6; i++) {
      int c = t + i * 256;
      int row2 = c / 768;
      int rem = c - row2 * 768;
      int wi = rem >> 3, p8 = rem & 7;
      const unsigned short* lsrc = &tbl[(row2 * 96 + wi) * 68 + p8 * 8];
      uint2 lo = *(const uint2*)lsrc;
      uint2 hi2 = *(const uint2*)(lsrc + 4);
      size_t ga = ((size_t)(h0 + 1 + row2) * 98 + (wi + 1)) * 256 + co0 + p8 * 8;
      uint4 vv; vv.x = lo.x; vv.y = lo.y; vv.z = hi2.x; vv.w = hi2.y;
      *(uint4*)&dstb[ga] = vv;
    }
  } else {
    // conv2: f32 plane-major output
    #pragma unroll
    for (int r = 0; r < 16; r++) {
      int row = (r & 3) + 8 * (r >> 2) + 4 * lhi;
      int co = co0 + mh * 32 + row;
      float bv = cb[co];
      size_t base = ((size_t)(b * 256 + co) * 96 + h) * 96;
      #pragma unroll
      for (int nn = 0; nn < 3; nn++) {
        out[base + nn * 32 + l31] = acc[nn][r] + bv;
      }
    }
  }
}

// ---------------------------------------------------------------------------
extern "C" void kernel_launch(void* const* d_in, const int* in_sizes, int n_in,
                              void* d_out, int out_size, void* d_ws, size_t ws_size,
                              hipStream_t stream)
{
  const float* fm    = (const float*)d_in[0];
  const float* para  = (const float*)d_in[1];
  const float* style = (const float*)d_in[2];
  const float* cw  = (const float*)d_in[3];
  const float* cb  = (const float*)d_in[4];
  const float* sw  = (const float*)d_in[5];
  const float* sb  = (const float*)d_in[6];
  const float* rw  = (const float*)d_in[7];
  const float* rb  = (const float*)d_in[8];
  const float* tw  = (const float*)d_in[9];
  const float* tb  = (const float*)d_in[10];
  const float* a1w = (const float*)d_in[11];
  const float* a1b = (const float*)d_in[12];
  const float* g1w = (const float*)d_in[13];
  const float* g1b = (const float*)d_in[14];
  const float* b1w = (const float*)d_in[15];
  const float* b1b = (const float*)d_in[16];
  const float* c1w = (const float*)d_in[17];
  const float* c1b = (const float*)d_in[18];
  const float* a2w = (const float*)d_in[19];
  const float* a2b = (const float*)d_in[20];
  const float* g2w = (const float*)d_in[21];
  const float* g2b = (const float*)d_in[22];
  const float* b2w = (const float*)d_in[23];
  const float* b2b = (const float*)d_in[24];
  const float* c2w = (const float*)d_in[25];
  const float* c2b = (const float*)d_in[26];

  float* outf = (float*)d_out;
  unsigned short* tbf16 = (unsigned short*)d_out;  // bf16 t (first half of d_out)

  unsigned short* xtbuf  = (unsigned short*)d_ws;                 // xt1
  unsigned short* xt2buf = xtbuf + (size_t)BATCH * XT_PLANE;      // xt2
  unsigned short* wf1    = xt2buf + (size_t)BATCH * XT_PLANE;
  unsigned short* wf2    = wf1 + 9 * 256 * 256;
  float* fws  = (float*)(wf2 + 9 * 256 * 256);
  float* warp = fws;                   // 4096
  float* gb1  = warp + 4 * 1024;       // 2048
  float* gb2  = gb1 + 2 * 1024;        // 2048
  float* nrm2 = gb2 + 2 * 1024;        // 2048
  float* pcbuf = nrm2 + 2 * 1024;      // 1024
  float* a1buf = pcbuf + 1024;         // 512
  float* a2buf = a1buf + 512;          // 512
  float* psum  = a2buf + 512;          // 98304 floats

  params_stage1_kernel<<<dim3(6, 4), 256, 0, stream>>>(para, style, cw, cb,
      a1w, a1b, a2w, a2b, pcbuf, a1buf, a2buf);
  params_stage2_kernel<<<dim3(16, 4), 256, 0, stream>>>(pcbuf, a1buf, a2buf,
      sw, sb, rw, rb, tw, tb, g1w, g1b, b1w, b1b, g2w, g2b, b2w, b2b,
      warp, gb1, gb2);
  prep_weights_kernel<<<512, 256, 0, stream>>>(c1w, c2w, wf1, wf2);
  adaat_kernel<<<1024, 256, 0, stream>>>(fm, warp, gb1, tbf16);
  transpose_kernel<<<dim3(98, 4), 256, 0, stream>>>(tbf16, xtbuf);
  conv_mfma_kernel<<<dim3(48, 4, 4), 256, 0, stream>>>(xtbuf, wf1, c1b,
      outf, xt2buf, psum);
  finalize_stats_kernel<<<4, 256, 0, stream>>>(psum, gb2, nrm2);
  norm2_kernel<<<dim3(98, 4), 256, 0, stream>>>(xt2buf, nrm2);
  conv_mfma_kernel<<<dim3(48, 4, 4), 256, 0, stream>>>(xt2buf, wf2, c2b,
      outf, nullptr, nullptr);
}

// Round 19
// 179.556 us; speedup vs baseline: 1.1158x; 1.0001x over previous
//
#include <hip/hip_runtime.h>
#include <hip/hip_bf16.h>
#include <cstddef>

#define BATCH 4
#define CH 256
#define HH 96
#define WW 96
#define HWN (HH*WW)               // 9216
#define NTOT (BATCH*CH*HWN)       // 9437184
#define XT_H 98
#define XT_W 98
#define XT_PLANE (XT_H*XT_W*CH)   // per-batch elements in xt (bf16)

typedef __attribute__((ext_vector_type(16))) float f32x16;
typedef __attribute__((ext_vector_type(8))) __bf16 bfrag;
typedef __attribute__((ext_vector_type(8))) unsigned short u16x8;

static __device__ __forceinline__ unsigned short f2bf(float f) {
  unsigned int u = __float_as_uint(f);
  unsigned int r = (u + 0x7fffu + ((u >> 16) & 1u)) >> 16;
  return (unsigned short)r;
}
static __device__ __forceinline__ float bf2f(unsigned short s) {
  return __uint_as_float(((unsigned int)s) << 16);
}

// async global->LDS, 16B per lane; LDS dest = wave-uniform base + lane*16
static __device__ __forceinline__ void gload16(const unsigned short* g,
                                               unsigned short* l) {
  __builtin_amdgcn_global_load_lds(
      (const __attribute__((address_space(1))) unsigned int*)g,
      (__attribute__((address_space(3))) unsigned int*)l, 16, 0, 0);
}

// ---------------------------------------------------------------------------
// Kernel 1a: stage-1 GEMVs, wide-parallel (unchanged R9).
// ---------------------------------------------------------------------------
__global__ __launch_bounds__(256) void params_stage1_kernel(
    const float* __restrict__ para, const float* __restrict__ style,
    const float* __restrict__ cw,  const float* __restrict__ cb,
    const float* __restrict__ a1w, const float* __restrict__ a1b,
    const float* __restrict__ a2w, const float* __restrict__ a2b,
    float* __restrict__ pcbuf, float* __restrict__ a1buf, float* __restrict__ a2buf)
{
  __shared__ float s_in[256];
  __shared__ float red[256];
  int part = blockIdx.x, b = blockIdx.y, t = threadIdx.x;
  s_in[t] = (part < 4) ? para[b*256 + t] : style[b*256 + t];
  __syncthreads();
  if (part < 4) {
    int o = t & 63, ks = t >> 6, co0 = part * 64;
    const float* wcol = cw + co0 + o;
    float acc = 0.f;
    #pragma unroll 8
    for (int i = 0; i < 64; i++) {
      int k = ks * 64 + i;
      acc = fmaf(s_in[k], wcol[k * 256], acc);
    }
    red[t] = acc;
    __syncthreads();
    if (t < 64) {
      float s = red[t] + red[t + 64] + red[t + 128] + red[t + 192];
      pcbuf[b*256 + co0 + t] = fmaxf(s + cb[co0 + t], 0.f);
    }
  } else {
    const float* w  = (part == 4) ? a1w : a2w;
    const float* bb = (part == 4) ? a1b : a2b;
    float* outp = (part == 4) ? a1buf : a2buf;
    int o = t & 127, ks = t >> 7;
    const float* wcol = w + o;
    float acc = 0.f;
    #pragma unroll 8
    for (int i = 0; i < 128; i++) {
      int k = ks * 128 + i;
      acc = fmaf(s_in[k], wcol[k * 128], acc);
    }
    red[t] = acc;
    __syncthreads();
    if (t < 128) {
      float s = red[t] + red[t + 128];
      outp[b*128 + t] = fmaxf(s + bb[t], 0.f);
    }
  }
}

// ---------------------------------------------------------------------------
// Kernel 1b: stage-2 params (unchanged R9).
// ---------------------------------------------------------------------------
__global__ __launch_bounds__(256) void params_stage2_kernel(
    const float* __restrict__ pcbuf, const float* __restrict__ a1buf,
    const float* __restrict__ a2buf,
    const float* __restrict__ sw,  const float* __restrict__ sb,
    const float* __restrict__ rw,  const float* __restrict__ rb,
    const float* __restrict__ tw,  const float* __restrict__ tb,
    const float* __restrict__ g1w, const float* __restrict__ g1b,
    const float* __restrict__ b1w, const float* __restrict__ b1b,
    const float* __restrict__ g2w, const float* __restrict__ g2b,
    const float* __restrict__ b2w, const float* __restrict__ b2b,
    float* __restrict__ warp, float* __restrict__ gb1, float* __restrict__ gb2)
{
  __shared__ float s_pc[256], s_a1[128], s_a2[128];
  __shared__ float red[8][4][16];
  int co0 = blockIdx.x * 16, b = blockIdx.y, t = threadIdx.x;
  s_pc[t] = pcbuf[b*256 + t];
  if (t < 128) s_a1[t] = a1buf[b*128 + t];
  else         s_a2[t - 128] = a2buf[b*128 + (t - 128)];
  __syncthreads();

  int cl = t & 15, klane = t >> 4;
  int c = co0 + cl;
  const float2* tw2 = (const float2*)tw;
  float ds = 0.f, dr = 0.f, dtx = 0.f, dty = 0.f;
  float g1 = 0.f, be1 = 0.f, g2 = 0.f, be2 = 0.f;
  #pragma unroll 4
  for (int kk = 0; kk < 16; kk++) {
    int i = klane * 16 + kk;
    float p = s_pc[i];
    ds  = fmaf(p, sw[i*256 + c], ds);
    dr  = fmaf(p, rw[i*256 + c], dr);
    float2 tv = tw2[i*256 + c];
    dtx = fmaf(p, tv.x, dtx);
    dty = fmaf(p, tv.y, dty);
  }
  #pragma unroll 4
  for (int kk = 0; kk < 8; kk++) {
    int i = klane * 8 + kk;
    float a = s_a1[i];
    g1  = fmaf(a, g1w[i*256 + c], g1);
    be1 = fmaf(a, b1w[i*256 + c], be1);
    float a2v = s_a2[i];
    g2  = fmaf(a2v, g2w[i*256 + c], g2);
    be2 = fmaf(a2v, b2w[i*256 + c], be2);
  }
  ds  += __shfl_down(ds, 32, 64);  ds  += __shfl_down(ds, 16, 64);
  dr  += __shfl_down(dr, 32, 64);  dr  += __shfl_down(dr, 16, 64);
  dtx += __shfl_down(dtx, 32, 64); dtx += __shfl_down(dtx, 16, 64);
  dty += __shfl_down(dty, 32, 64); dty += __shfl_down(dty, 16, 64);
  g1  += __shfl_down(g1, 32, 64);  g1  += __shfl_down(g1, 16, 64);
  be1 += __shfl_down(be1, 32, 64); be1 += __shfl_down(be1, 16, 64);
  g2  += __shfl_down(g2, 32, 64);  g2  += __shfl_down(g2, 16, 64);
  be2 += __shfl_down(be2, 32, 64); be2 += __shfl_down(be2, 16, 64);
  int wv = t >> 6;
  if ((t & 63) < 16) {
    red[0][wv][cl] = ds;  red[1][wv][cl] = dr;
    red[2][wv][cl] = dtx; red[3][wv][cl] = dty;
    red[4][wv][cl] = g1;  red[5][wv][cl] = be1;
    red[6][wv][cl] = g2;  red[7][wv][cl] = be2;
  }
  __syncthreads();
  if (t < 16) {
    float v[8];
    #pragma unroll
    for (int o = 0; o < 8; o++)
      v[o] = red[o][0][t] + red[o][1][t] + red[o][2][t] + red[o][3][t];
    int cc = co0 + t;
    int bc = b*256 + cc;
    float scale = 2.f / (1.f + expf(-(v[0] + sb[cc])));
    float ang = tanhf(v[1] + rb[cc]) * 3.14159f;
    float sn, cs;
    sincosf(ang, &sn, &cs);
    warp[bc*4 + 0] = cs * scale;
    warp[bc*4 + 1] = sn * scale;
    warp[bc*4 + 2] = tanhf(v[2] + tb[2*cc]);
    warp[bc*4 + 3] = tanhf(v[3] + tb[2*cc + 1]);
    gb1[bc*2]     = v[4] + g1b[cc];
    gb1[bc*2 + 1] = v[5] + b1b[cc];
    gb2[bc*2]     = v[6] + g2b[cc];
    gb2[bc*2 + 1] = v[7] + b2b[cc];
  }
}

// ---------------------------------------------------------------------------
// Kernel 2: weight preconversion (unchanged).
// wf[coblk4][ks16][tap9][m2][lane64][8]
// ---------------------------------------------------------------------------
__global__ __launch_bounds__(256) void prep_weights_kernel(
    const float* __restrict__ w1, const float* __restrict__ w2,
    unsigned short* __restrict__ wf1, unsigned short* __restrict__ wf2)
{
  int co = blockIdx.x & 255;
  const float* src = (blockIdx.x < 256) ? w1 : w2;
  unsigned short* dst = (blockIdx.x < 256) ? wf1 : wf2;
  int ci = threadIdx.x;
  int coblk = co >> 6, m = (co >> 5) & 1;
  int l = (co & 31) | (((ci >> 3) & 1) << 5);
  int ks = ci >> 4, j = ci & 7;
  const float* p = src + ((size_t)co * 256 + ci) * 9;
  #pragma unroll
  for (int tap = 0; tap < 9; tap++) {
    size_t idx = (((size_t)((coblk * 16 + ks) * 9 + tap) * 2 + m) * 64 + l) * 8 + j;
    dst[idx] = f2bf(p[tap]);
  }
}

// ---------------------------------------------------------------------------
// Kernel 3: AdaAT warp + fused stats + AdaIN-1 + lrelu + bf16 cvt (R14).
// ---------------------------------------------------------------------------
__global__ __launch_bounds__(256) void adaat_kernel(
    const float* __restrict__ fm, const float* __restrict__ warp,
    const float* __restrict__ gb1, unsigned short* __restrict__ tout)
{
  __shared__ float s[96 * 100];
  int bc = blockIdx.x;
  int b = bc >> 8, c = bc & 255;
  float csc = warp[bc*4 + 0], ssc = warp[bc*4 + 1];
  float tx = warp[bc*4 + 2], ty = warp[bc*4 + 3];

  const float axw = csc * (96.f / 95.f);
  const float axh = -ssc * (96.f / 95.f);
  const float ax0 = 48.f * (tx - csc + ssc) + 47.5f;
  const float ayw = ssc * (96.f / 95.f);
  const float ayh = csc * (96.f / 95.f);
  const float ay0 = 48.f * (ty - ssc - csc) + 47.5f;

  float iz = 256.f * (float)c / 255.f - 0.5f;
  float z0f = floorf(iz);
  float wz = iz - z0f;
  int z0 = (int)z0f;
  const float* p0 = (z0 >= 0) ? fm + (size_t)(b*256 + z0) * HWN : nullptr;
  const float* p1 = (z0 + 1 < 256) ? fm + (size_t)(b*256 + z0 + 1) * HWN : nullptr;
  float w0 = 1.f - wz, w1 = wz;

  int t = threadIdx.x;
  const float4* q0 = (const float4*)p0;
  const float4* q1 = (const float4*)p1;
  for (int i = t; i < 2304; i += 256) {
    int row = i / 24, col = i - row * 24;
    float4 r = {0.f, 0.f, 0.f, 0.f};
    if (q0) {
      float4 v = q0[i];
      r.x = w0 * v.x; r.y = w0 * v.y; r.z = w0 * v.z; r.w = w0 * v.w;
    }
    if (q1) {
      float4 v = q1[i];
      r.x = fmaf(w1, v.x, r.x); r.y = fmaf(w1, v.y, r.y);
      r.z = fmaf(w1, v.z, r.z); r.w = fmaf(w1, v.w, r.w);
    }
    *(float4*)&s[row * 100 + col * 4] = r;
  }
  __syncthreads();

  int h = t / 96, w = t - (t / 96) * 96;
  float vals[36];
  float sum = 0.f, sumsq = 0.f;
  #pragma unroll
  for (int k = 0; k < 36; k++) {
    float ix = fmaf(axw, (float)w, fmaf(axh, (float)h, ax0));
    float iy = fmaf(ayw, (float)w, fmaf(ayh, (float)h, ay0));
    float x0f = floorf(ix), y0f = floorf(iy);
    float wx = ix - x0f, wy = iy - y0f;
    int x0 = (int)x0f, y0 = (int)y0f;
    int x0c = min(max(x0, 0), 95), x1c = min(max(x0 + 1, 0), 95);
    int y0c = min(max(y0, 0), 95), y1c = min(max(y0 + 1, 0), 95);
    bool vx0 = (unsigned)x0 < 96u, vx1 = (unsigned)(x0 + 1) < 96u;
    bool vy0 = (unsigned)y0 < 96u, vy1 = (unsigned)(y0 + 1) < 96u;
    float a00 = s[y0c * 100 + x0c], a01 = s[y0c * 100 + x1c];
    float a10 = s[y1c * 100 + x0c], a11 = s[y1c * 100 + x1c];
    float wxm = 1.f - wx, wym = 1.f - wy;
    float w00 = (vy0 && vx0) ? wym * wxm : 0.f;
    float w01 = (vy0 && vx1) ? wym * wx  : 0.f;
    float w10 = (vy1 && vx0) ? wy * wxm  : 0.f;
    float w11 = (vy1 && vx1) ? wy * wx   : 0.f;
    float v = w00 * a00;
    v = fmaf(w01, a01, v);
    v = fmaf(w10, a10, v);
    v = fmaf(w11, a11, v);
    vals[k] = v;
    sum += v;
    sumsq = fmaf(v, v, sumsq);
    int wn = w + 64;
    int carry = (wn >= 96) ? 1 : 0;
    w = wn - (carry ? 96 : 0);
    h += 2 + carry;
  }

  for (int off = 32; off > 0; off >>= 1) {
    sum   += __shfl_down(sum, off, 64);
    sumsq += __shfl_down(sumsq, off, 64);
  }
  __shared__ float rs[4], rq[4], sbi[2];
  int lane = t & 63, wvi = t >> 6;
  if (lane == 0) { rs[wvi] = sum; rq[wvi] = sumsq; }
  __syncthreads();
  if (t == 0) {
    float S = rs[0] + rs[1] + rs[2] + rs[3];
    float Q = rq[0] + rq[1] + rq[2] + rq[3];
    float m = S * (1.f / 9216.f);
    float var = Q * (1.f / 9216.f) - m * m;
    float rstd = rsqrtf(var + 1e-5f);
    float sc = (1.f + gb1[bc*2]) * rstd;
    sbi[0] = sc;
    sbi[1] = gb1[bc*2 + 1] - m * sc;
  }
  __syncthreads();
  float sc = sbi[0], bi = sbi[1];
  unsigned short* dst = tout + (size_t)bc * HWN + t;
  #pragma unroll
  for (int k = 0; k < 36; k++) {
    float y = fmaf(vals[k], sc, bi);
    y = (y >= 0.f) ? y : 0.2f * y;
    dst[k * 256] = f2bf(y);
  }
}

// ---------------------------------------------------------------------------
// Kernel 4: finalize per-(b,co) stats from conv1 partials (unchanged).
// ---------------------------------------------------------------------------
__global__ __launch_bounds__(256) void finalize_stats_kernel(
    const float* __restrict__ psum, const float* __restrict__ gb,
    float* __restrict__ nrm)
{
  int bc = blockIdx.x * 256 + threadIdx.x;
  int b = bc >> 8, co = bc & 255;
  float S = 0.f, Q = 0.f;
  for (int j = 0; j < 96; j++) {
    const float* p = psum + ((((size_t)b * 48 + (j >> 1)) * 2 + (j & 1)) * 256 + co) * 2;
    S += p[0];
    Q += p[1];
  }
  float m = S * (1.f / 9216.f);
  float var = Q * (1.f / 9216.f) - m * m;
  float rstd = rsqrtf(var + 1e-5f);
  float sc = (1.f + gb[bc*2]) * rstd;
  nrm[bc*2] = sc;
  nrm[bc*2 + 1] = gb[bc*2 + 1] - m * sc;
}

// ---------------------------------------------------------------------------
// Kernel 5: pure bf16 transpose t(plane-major) -> xt layout + borders (R14).
// ---------------------------------------------------------------------------
__global__ __launch_bounds__(256) void transpose_kernel(
    const unsigned short* __restrict__ tb, unsigned short* __restrict__ xt)
{
  int hi = blockIdx.x;
  int b  = blockIdx.y;
  unsigned short* dst = xt + (size_t)b * XT_PLANE + (size_t)hi * (XT_W * CH);
  int t = threadIdx.x;
  int h = hi - 1;
  u16x8 zero = {0,0,0,0,0,0,0,0};
  if (h < 0 || h >= 96) {
    for (int c = t; c < XT_W * CH / 8; c += 256) ((u16x8*)dst)[c] = zero;
    return;
  }
  __shared__ unsigned short s[96 * 256];  // [w][ci]
  int ci = t;
  const unsigned short* src = tb + ((size_t)(b*256 + ci)) * HWN + h * 96;
  #pragma unroll
  for (int wg = 0; wg < 12; wg++) {
    u16x8 v = *(const u16x8*)(src + wg * 8);
    #pragma unroll
    for (int j = 0; j < 8; j++) s[(wg*8 + j) * 256 + ci] = v[j];
  }
  __syncthreads();
  for (int c = t; c < 98 * 32; c += 256) {
    int w = c >> 5, p = c & 31;
    u16x8 v = zero;
    if (w >= 1 && w <= 96) v = *(const u16x8*)&s[(w - 1) * 256 + p * 8];
    ((u16x8*)dst)[c] = v;
  }
}

// ---------------------------------------------------------------------------
// Kernel 5b: elementwise AdaIN-2 + lrelu on bf16 xt2, in place (unchanged).
// ---------------------------------------------------------------------------
__global__ __launch_bounds__(256) void norm2_kernel(
    unsigned short* __restrict__ xt, const float* __restrict__ nrm)
{
  int hi = blockIdx.x, b = blockIdx.y;
  unsigned short* row = xt + (size_t)b * XT_PLANE + (size_t)hi * (XT_W * CH);
  int t = threadIdx.x;
  u16x8 zero = {0,0,0,0,0,0,0,0};
  if (hi == 0 || hi == 97) {
    for (int c = t; c < XT_W * CH / 8; c += 256) ((u16x8*)row)[c] = zero;
    return;
  }
  int p = t & 31;
  float sc[8], bi[8];
  #pragma unroll
  for (int j = 0; j < 8; j++) {
    int co = p * 8 + j;
    sc[j] = nrm[(b*256 + co)*2];
    bi[j] = nrm[(b*256 + co)*2 + 1];
  }
  for (int wi = t >> 5; wi < 98; wi += 8) {
    int c = wi * 32 + p;
    if (wi == 0 || wi == 97) { ((u16x8*)row)[c] = zero; continue; }
    u16x8 v = ((u16x8*)row)[c];
    u16x8 o;
    #pragma unroll
    for (int j = 0; j < 8; j++) {
      float x = bf2f(v[j]);
      float y = fmaf(x, sc[j], bi[j]);
      y = (y >= 0.f) ? y : 0.2f * y;
      o[j] = f2bf(y);
    }
    ((u16x8*)row)[c] = o;
  }
}

// ---------------------------------------------------------------------------
// Kernel 6: R17-exact conv (no setprio). Epilogue: conv1 writes bf16
// transposed (LDS bounce) + stats partials; conv2 writes f32 plane-major.
// ---------------------------------------------------------------------------
__global__ __launch_bounds__(256, 3) void conv_mfma_kernel(
    const unsigned short* __restrict__ xt,   // input [4][98][98][256] bf16
    const unsigned short* __restrict__ wf,   // frag layout (see prep)
    const float* __restrict__ cb,
    float* __restrict__ out,                 // f32 output (conv2 path)
    unsigned short* __restrict__ xt2,        // bf16 transposed output (conv1)
    float* __restrict__ psum)                // partials or nullptr
{
  __shared__ __align__(16) unsigned short s_in[2][6528];

  int hb = blockIdx.x, coblk = blockIdx.y, b = blockIdx.z;
  int co0 = coblk * 64, h0 = hb * 2;
  int t = threadIdx.x, lane = t & 63, wv = t >> 6;
  int rw = wv >> 1, mh = wv & 1;
  int l31 = lane & 31, lhi = lane >> 5;
  const unsigned short* xtb = xt + (size_t)b * XT_PLANE;

  int pre_g[4];
  #pragma unroll
  for (int i = 0; i < 4; i++) {
    int c = t + i * 256;
    if (c < 784) {
      int r = c / 196;
      int rem = c - r * 196;
      int half = rem / 98;
      int w = rem - half * 98;
      pre_g[i] = ((h0 + r) * 98 + w) * 256 + half * 8;
    }
  }

  f32x16 acc[3];
  #pragma unroll
  for (int nn = 0; nn < 3; nn++)
    #pragma unroll
    for (int i = 0; i < 16; i++) acc[nn][i] = 0.f;

  const unsigned short* wfb = wf + (size_t)(coblk * 16) * 9216 + mh * 512 + lane * 8;

  {
    #pragma unroll
    for (int i = 0; i < 3; i++)
      gload16(xtb + pre_g[i], &s_in[0][(i * 256 + wv * 64) * 8]);
    u16x8 tail0;
    if (t < 16) tail0 = *(const u16x8*)(xtb + pre_g[3]);
    if (t < 16) *(u16x8*)(&s_in[0][(768 + t) * 8]) = tail0;
  }
  bfrag wa[9];
  #pragma unroll
  for (int tap = 0; tap < 9; tap++) wa[tap] = *(const bfrag*)(wfb + tap * 1024);
  __syncthreads();

  int buf = 0;
  u16x8 tail;
  #pragma unroll 1
  for (int ks = 0; ks < 16; ks++) {
    if (ks < 15) {
      int cib = (ks + 1) * 16;
      unsigned short* nb = s_in[buf ^ 1];
      #pragma unroll
      for (int i = 0; i < 3; i++)
        gload16(xtb + pre_g[i] + cib, &nb[(i * 256 + wv * 64) * 8]);
      if (t < 16) tail = *(const u16x8*)(xtb + pre_g[3] + cib);
    }
    const unsigned short* sb = s_in[buf];
    int ksn = (ks < 15) ? (ks + 1) : 15;
    const unsigned short* wkn = wfb + (size_t)ksn * 9216;
    #pragma unroll
    for (int ky = 0; ky < 3; ky++) {
      const unsigned short* srow = sb + (((rw + ky) * 2 + lhi) * 98) * 8;
      bfrag bb[9];
      #pragma unroll
      for (int kx = 0; kx < 3; kx++)
        #pragma unroll
        for (int nn = 0; nn < 3; nn++)
          bb[kx * 3 + nn] = *(const bfrag*)(srow + (nn * 32 + kx + l31) * 8);
      #pragma unroll
      for (int kx = 0; kx < 3; kx++) {
        int tap = ky * 3 + kx;
        acc[0] = __builtin_amdgcn_mfma_f32_32x32x16_bf16(wa[tap], bb[kx*3+0], acc[0], 0, 0, 0);
        acc[1] = __builtin_amdgcn_mfma_f32_32x32x16_bf16(wa[tap], bb[kx*3+1], acc[1], 0, 0, 0);
        acc[2] = __builtin_amdgcn_mfma_f32_32x32x16_bf16(wa[tap], bb[kx*3+2], acc[2], 0, 0, 0);
        wa[tap] = *(const bfrag*)(wkn + tap * 1024);
      }
    }
    if (ks < 15 && t < 16) *(u16x8*)(&s_in[buf ^ 1][(768 + t) * 8]) = tail;
    __syncthreads();
    buf ^= 1;
  }

  int h = h0 + rw;
  if (psum) {
    // conv1: bf16 transposed output via LDS bounce + stats partials
    unsigned short* tbl = (unsigned short*)s_in;   // [2 rows][96 px][68 co-pad]
    float bsum[16], bsq[16];
    #pragma unroll
    for (int r = 0; r < 16; r++) {
      int row = (r & 3) + 8 * (r >> 2) + 4 * lhi;
      int col = mh * 32 + row;
      float bv = cb[co0 + col];
      float s = 0.f, q = 0.f;
      #pragma unroll
      for (int nn = 0; nn < 3; nn++) {
        float y = acc[nn][r] + bv;
        int px = nn * 32 + l31;
        tbl[(rw * 96 + px) * 68 + col] = f2bf(y);
        s += y;
        q = fmaf(y, y, q);
      }
      bsum[r] = s; bsq[r] = q;
    }
    #pragma unroll
    for (int r = 0; r < 16; r++) {
      float s = bsum[r], q = bsq[r];
      #pragma unroll
      for (int off = 16; off > 0; off >>= 1) {
        s += __shfl_xor(s, off, 64);
        q += __shfl_xor(q, off, 64);
      }
      bsum[r] = s; bsq[r] = q;
    }
    if (l31 == 0) {
      float* pp = psum + ((((size_t)b * 48 + hb) * 2 + rw) * 256) * 2;
      #pragma unroll
      for (int r = 0; r < 16; r++) {
        int row = (r & 3) + 8 * (r >> 2) + 4 * lhi;
        int co = co0 + mh * 32 + row;
        pp[co * 2]     = bsum[r];
        pp[co * 2 + 1] = bsq[r];
      }
    }
    __syncthreads();
    unsigned short* dstb = xt2 + (size_t)b * XT_PLANE;
    #pragma unroll
    for (int i = 0; i < 6; i++) {
      int c = t + i * 256;
      int row2 = c / 768;
      int rem = c - row2 * 768;
      int wi = rem >> 3, p8 = rem & 7;
      const unsigned short* lsrc = &tbl[(row2 * 96 + wi) * 68 + p8 * 8];
      uint2 lo = *(const uint2*)lsrc;
      uint2 hi2 = *(const uint2*)(lsrc + 4);
      size_t ga = ((size_t)(h0 + 1 + row2) * 98 + (wi + 1)) * 256 + co0 + p8 * 8;
      uint4 vv; vv.x = lo.x; vv.y = lo.y; vv.z = hi2.x; vv.w = hi2.y;
      *(uint4*)&dstb[ga] = vv;
    }
  } else {
    // conv2: f32 plane-major output
    #pragma unroll
    for (int r = 0; r < 16; r++) {
      int row = (r & 3) + 8 * (r >> 2) + 4 * lhi;
      int co = co0 + mh * 32 + row;
      float bv = cb[co];
      size_t base = ((size_t)(b * 256 + co) * 96 + h) * 96;
      #pragma unroll
      for (int nn = 0; nn < 3; nn++) {
        out[base + nn * 32 + l31] = acc[nn][r] + bv;
      }
    }
  }
}

// ---------------------------------------------------------------------------
extern "C" void kernel_launch(void* const* d_in, const int* in_sizes, int n_in,
                              void* d_out, int out_size, void* d_ws, size_t ws_size,
                              hipStream_t stream)
{
  const float* fm    = (const float*)d_in[0];
  const float* para  = (const float*)d_in[1];
  const float* style = (const float*)d_in[2];
  const float* cw  = (const float*)d_in[3];
  const float* cb  = (const float*)d_in[4];
  const float* sw  = (const float*)d_in[5];
  const float* sb  = (const float*)d_in[6];
  const float* rw  = (const float*)d_in[7];
  const float* rb  = (const float*)d_in[8];
  const float* tw  = (const float*)d_in[9];
  const float* tb  = (const float*)d_in[10];
  const float* a1w = (const float*)d_in[11];
  const float* a1b = (const float*)d_in[12];
  const float* g1w = (const float*)d_in[13];
  const float* g1b = (const float*)d_in[14];
  const float* b1w = (const float*)d_in[15];
  const float* b1b = (const float*)d_in[16];
  const float* c1w = (const float*)d_in[17];
  const float* c1b = (const float*)d_in[18];
  const float* a2w = (const float*)d_in[19];
  const float* a2b = (const float*)d_in[20];
  const float* g2w = (const float*)d_in[21];
  const float* g2b = (const float*)d_in[22];
  const float* b2w = (const float*)d_in[23];
  const float* b2b = (const float*)d_in[24];
  const float* c2w = (const float*)d_in[25];
  const float* c2b = (const float*)d_in[26];

  float* outf = (float*)d_out;
  unsigned short* tbf16 = (unsigned short*)d_out;  // bf16 t (first half of d_out)

  unsigned short* xtbuf  = (unsigned short*)d_ws;                 // xt1
  unsigned short* xt2buf = xtbuf + (size_t)BATCH * XT_PLANE;      // xt2
  unsigned short* wf1    = xt2buf + (size_t)BATCH * XT_PLANE;
  unsigned short* wf2    = wf1 + 9 * 256 * 256;
  float* fws  = (float*)(wf2 + 9 * 256 * 256);
  float* warp = fws;                   // 4096
  float* gb1  = warp + 4 * 1024;       // 2048
  float* gb2  = gb1 + 2 * 1024;        // 2048
  float* nrm2 = gb2 + 2 * 1024;        // 2048
  float* pcbuf = nrm2 + 2 * 1024;      // 1024
  float* a1buf = pcbuf + 1024;         // 512
  float* a2buf = a1buf + 512;          // 512
  float* psum  = a2buf + 512;          // 196608 floats

  params_stage1_kernel<<<dim3(6, 4), 256, 0, stream>>>(para, style, cw, cb,
      a1w, a1b, a2w, a2b, pcbuf, a1buf, a2buf);
  params_stage2_kernel<<<dim3(16, 4), 256, 0, stream>>>(pcbuf, a1buf, a2buf,
      sw, sb, rw, rb, tw, tb, g1w, g1b, b1w, b1b, g2w, g2b, b2w, b2b,
      warp, gb1, gb2);
  prep_weights_kernel<<<512, 256, 0, stream>>>(c1w, c2w, wf1, wf2);
  adaat_kernel<<<1024, 256, 0, stream>>>(fm, warp, gb1, tbf16);
  transpose_kernel<<<dim3(98, 4), 256, 0, stream>>>(tbf16, xtbuf);
  conv_mfma_kernel<<<dim3(48, 4, 4), 256, 0, stream>>>(xtbuf, wf1, c1b,
      outf, xt2buf, psum);
  finalize_stats_kernel<<<4, 256, 0, stream>>>(psum, gb2, nrm2);
  norm2_kernel<<<dim3(98, 4), 256, 0, stream>>>(xt2buf, nrm2);
  conv_mfma_kernel<<<dim3(48, 4, 4), 256, 0, stream>>>(xt2buf, wf2, c2b,
      outf, nullptr, nullptr);
}